// Round 9
// baseline (438.594 us; speedup 1.0000x reference)
//
#include <hip/hip_runtime.h>
#include <hip/hip_bf16.h>

// ---------------------------------------------------------------------------
// 2-layer GCN, atomic-free CSC gather, bf16 payloads + bf16 MFMA GEMMs.
// dis[] is folded into the gathered payloads (xb = x*dis, zb = z*dis), so
// edge records are source-index-only (4 B). Aggregation at target c:
//   A·v|_c = dis[c] * (sum_r payload[r] + payload[c])
// Layer 1: h = relu((A x) @ W1 + b1)   [reassociated]
// Layer 2: out = A (h @ W2) + b2
//
// R1: LDS-aggregated bucket histogram replaces 1.6M global atomics.
// R5: build chain widened (fill2 1024 thr, binfill 512 thr).
// R8: SLAB buckets — k_bcount/k_bscanw deleted; fill2 emits int2 rpse.
// R9: FEATURE-SLICED gather1. xb stored slice-major [8][N][32B]; block's
// slice = blockIdx%8 (round-robin block->XCD mapping) so each XCD's L2
// caches only its 3.2MB slice (fits in 4MB L2) instead of streaming the
// whole 25.6MB table (8x22MB=190MB fetch -> ~85MB). Wave = 8 edge-groups
// x 8 feature-lanes, shfl_xor reduce; xab output stays row-major.
// ---------------------------------------------------------------------------

#define FB_SHIFT 9              // 512 nodes per bucket; r<2^17 packs with c_local
#define SLAB_SHIFT 14           // 16384 edge slots per bucket slab (~1.9x max)

__device__ __forceinline__ unsigned bf16rn(float f) {
    unsigned x = __float_as_uint(f);
    unsigned r = ((x >> 16) & 1u) + 0x7fffu;   // RNE
    return (x + r) >> 16;
}
__device__ __forceinline__ float bf_lo(unsigned u) { return __uint_as_float(u << 16); }
__device__ __forceinline__ float bf_hi(unsigned u) { return __uint_as_float(u & 0xffff0000u); }

typedef __bf16 bf16x8 __attribute__((ext_vector_type(8)));
typedef float  f32x4  __attribute__((ext_vector_type(4)));

// ---- multisplit: bin edges by target bucket into fixed slabs --------------
__global__ __launch_bounds__(512) void k_binfill(const int* __restrict__ row,
                                                 const int* __restrict__ col,
                                                 int* __restrict__ bcur,
                                                 unsigned* __restrict__ bins, int E,
                                                 int nEB,
                                                 const float* __restrict__ W1,
                                                 const float* __restrict__ W2,
                                                 unsigned* __restrict__ Wt,
                                                 unsigned* __restrict__ W2t) {
    const int tid = threadIdx.x;

    if (blockIdx.x >= nEB) {            // ---- W-conversion tail blocks ----
        int w = (blockIdx.x - nEB) * 512 + tid;   // 0..11263
        if (w < 8192) {
            int n = w >> 6, kk = (w & 63) * 2;
            unsigned lo = bf16rn(W1[(size_t)kk * 128 + n]);
            unsigned hi = bf16rn(W1[(size_t)(kk + 1) * 128 + n]);
            Wt[w] = lo | (hi << 16);
        } else if (w < 8192 + 3072) {
            int u = w - 8192;
            int n = u >> 6, kk = (u & 63) * 2;
            unsigned lo = 0, hi = 0;
            if (n < 40) {
                lo = bf16rn(W2[(size_t)kk * 40 + n]);
                hi = bf16rn(W2[(size_t)(kk + 1) * 40 + n]);
            }
            W2t[u] = lo | (hi << 16);
        }
        return;
    }

    __shared__ int hist[256];
    __shared__ int scn[256];
    __shared__ int gbase[256];
    __shared__ int rcnt[256];
    __shared__ unsigned stage[4096];
    __shared__ unsigned char bkts[4096];

    const int base = blockIdx.x * 4096;

    if (tid < 256) { hist[tid] = 0; rcnt[tid] = 0; }
    __syncthreads();

    unsigned mypk[8];
    int      myb[8];
#pragma unroll
    for (int k = 0; k < 8; ++k) {
        int e = base + k * 512 + tid;
        if (e < E) {
            int r = row[e], c = col[e];
            int b = c >> FB_SHIFT;
            mypk[k] = ((unsigned)r << FB_SHIFT) | (unsigned)(c & ((1 << FB_SHIFT) - 1));
            myb[k] = b;
            atomicAdd(&hist[b], 1);
        } else {
            myb[k] = -1;
        }
    }
    __syncthreads();

    int v = 0;
    if (tid < 256) { v = hist[tid]; scn[tid] = v; }
    __syncthreads();
#pragma unroll
    for (int off = 1; off < 256; off <<= 1) {
        int t = (tid >= off && tid < 256) ? scn[tid - off] : 0;
        __syncthreads();
        if (tid < 256) scn[tid] += t;
        __syncthreads();
    }
    if (tid < 256) {
        int excl = scn[tid] - v;
        scn[tid] = excl;
    }
    __syncthreads();

#pragma unroll
    for (int k = 0; k < 8; ++k) {
        int b = myb[k];
        if (b >= 0) {
            int slot = scn[b] + atomicAdd(&rcnt[b], 1);
            stage[slot] = mypk[k];
            bkts[slot] = (unsigned char)b;
        }
    }

    if (tid < 256 && hist[tid] > 0) gbase[tid] = atomicAdd(&bcur[tid], hist[tid]);
    __syncthreads();

    int total = scn[255] + hist[255];
    const int cap = 1 << SLAB_SHIFT;
    for (int s = tid; s < total; s += 512) {
        unsigned u = stage[s];
        int b = bkts[s];
        int off = gbase[b] + (s - scn[b]);
        if (off < cap)                              // clamp (pathological only)
            bins[((size_t)b << SLAB_SHIFT) + off] = u;
    }
}

// ---- per-bucket: degree count + local scan + scatter; emits rpse + dis ----
__global__ __launch_bounds__(1024) void k_fill2(const unsigned* __restrict__ bins,
                                                const int* __restrict__ bcur,
                                                int2* __restrict__ rpse,
                                                float* __restrict__ dis,
                                                int* __restrict__ pair, int N) {
    __shared__ int cnt[512];
    __shared__ int lcur[512];
    __shared__ int ssum[256];
    const int tid = threadIdx.x;
    const int b = blockIdx.x;
    const int n0 = b << FB_SHIFT;
    const int start = b << SLAB_SHIFT;
    int count = bcur[b];
    if (count > (1 << SLAB_SHIFT)) count = 1 << SLAB_SHIFT;
    const int end = start + count;

    if (tid < 512) cnt[tid] = 0;
    __syncthreads();

    for (int i = start + tid; i < end; i += 1024)
        atomicAdd(&cnt[bins[i] & ((1 << FB_SHIFT) - 1)], 1);
    __syncthreads();

    int c0 = 0, c1 = 0, vsum = 0;
    if (tid < 256) {
        c0 = cnt[2 * tid]; c1 = cnt[2 * tid + 1];
        vsum = c0 + c1;
        ssum[tid] = vsum;
    }
    __syncthreads();
#pragma unroll
    for (int off = 1; off < 256; off <<= 1) {
        int u = (tid >= off && tid < 256) ? ssum[tid - off] : 0;
        __syncthreads();
        if (tid < 256) ssum[tid] += u;
        __syncthreads();
    }
    if (tid < 256) {
        int e0 = start + ssum[tid] - vsum;
        int e1 = e0 + c0;
        lcur[2 * tid] = e0;
        lcur[2 * tid + 1] = e1;
        int node0 = n0 + 2 * tid;
        int node1 = node0 + 1;
        if (node0 < N) {
            rpse[node0] = make_int2(e0, e1);
            dis[node0] = rsqrtf((float)(c0 + 1));   // +1 self-loop
        }
        if (node1 < N) {
            rpse[node1] = make_int2(e1, e1 + c1);
            dis[node1] = rsqrtf((float)(c1 + 1));
        }
    }
    __syncthreads();

    for (int i = start + tid; i < end; i += 1024) {
        unsigned u = bins[i];
        int pos = atomicAdd(&lcur[u & ((1 << FB_SHIFT) - 1)], 1);
        pair[pos] = (int)(u >> FB_SHIFT);
    }
}

// ---- x -> xbs (slice-major [8][N][8 uints]) = bf16x2(x * dis) -------------
__global__ __launch_bounds__(256) void k_cvtx(const float* __restrict__ x,
                                              const float* __restrict__ dis,
                                              unsigned* __restrict__ xbs, int N) {
    int i = blockIdx.x * 256 + threadIdx.x;
    if (i >= N * 32) return;
    int n = i >> 5;                 // node
    int k2 = (i & 31) * 2;          // uint index within row (even)
    float4 v = ((const float4*)x)[i];
    float d = dis[n];
    uint2 o;
    o.x = bf16rn(v.x * d) | (bf16rn(v.y * d) << 16);
    o.y = bf16rn(v.z * d) | (bf16rn(v.w * d) << 16);
    int s = k2 >> 3, f = k2 & 7;    // slice, uint-in-slice (f even, f+1 same slice)
    *(uint2*)(xbs + ((size_t)s * N + n) * 8 + f) = o;
}

// ---- gather layer 1, feature-sliced ---------------------------------------
// Block slice = blockIdx%8 (round-robin block->XCD): each XCD's L2 holds its
// own 3.2MB slice of xbs. Wave = 8 edge-groups x 8 feature-lanes; per node:
// gather 8 edges/vmem, shfl_xor(8/16/32) reduce, eg==0 writes the 32B slice
// of row-major xab.
__global__ __launch_bounds__(256) void k_gather1s(const unsigned* __restrict__ xbs,
                                                  const int2* __restrict__ rpse,
                                                  const int* __restrict__ pair,
                                                  const float* __restrict__ dis,
                                                  unsigned* __restrict__ xab, int N) {
    const int bid = blockIdx.x;
    const int s = bid & 7;
    const int wv = threadIdx.x >> 6;
    const int gw = (bid >> 3) * 4 + wv;
    if (gw >= N) return;
    const int lane = threadIdx.x & 63;
    const int eg = lane >> 3;       // edge group 0..7
    const int fl = lane & 7;        // uint within 32B slice

    const unsigned* base = xbs + (size_t)s * N * 8;

    float ax = 0.f, ay = 0.f;
    if (eg == 0) {                  // self term (rows pre-scaled by dis)
        unsigned u = base[(size_t)gw * 8 + fl];
        ax = bf_lo(u); ay = bf_hi(u);
    }

    int2 rp = rpse[gw];
    int j = rp.x;
    const int je = rp.y;

    for (; j + 15 < je; j += 16) {          // 16 edges, 2 per lane-group
        int r0 = pair[j + eg];
        int r1 = pair[j + 8 + eg];
        unsigned u0 = base[(size_t)r0 * 8 + fl];
        unsigned u1 = base[(size_t)r1 * 8 + fl];
        ax += bf_lo(u0); ay += bf_hi(u0);
        ax += bf_lo(u1); ay += bf_hi(u1);
    }
    for (; j + 7 < je; j += 8) {            // 8 edges
        int r0 = pair[j + eg];
        unsigned u0 = base[(size_t)r0 * 8 + fl];
        ax += bf_lo(u0); ay += bf_hi(u0);
    }
    if (j + eg < je) {                      // tail < 8 edges
        int r0 = pair[j + eg];
        unsigned u0 = base[(size_t)r0 * 8 + fl];
        ax += bf_lo(u0); ay += bf_hi(u0);
    }

    // reduce across the 8 edge-groups (stride 8, 16, 32)
    ax += __shfl_xor(ax, 8, 64);
    ay += __shfl_xor(ay, 8, 64);
    ax += __shfl_xor(ax, 16, 64);
    ay += __shfl_xor(ay, 16, 64);
    ax += __shfl_xor(ax, 32, 64);
    ay += __shfl_xor(ay, 32, 64);

    if (eg == 0) {
        float dv = dis[gw];
        xab[(size_t)gw * 64 + s * 8 + fl] =
            bf16rn(dv * ax) | (bf16rn(dv * ay) << 16);
    }
}

// ---- fused GEMM1+GEMM2 (MFMA bf16) ----------------------------------------
// h = relu(xab @ W1t^T + b1)  (h kept in LDS, never hits global)
// Zb[M, pitch 32] = bf16( (h @ W2t^T) * dis[row] )  (20 uints used, 12 pad)
__global__ __launch_bounds__(256) void k_gemm12(const unsigned* __restrict__ Ab,
                                                const unsigned* __restrict__ Wt,
                                                const unsigned* __restrict__ W2t,
                                                const float* __restrict__ bias,
                                                const float* __restrict__ dis,
                                                unsigned* __restrict__ Zb, int M) {
    __shared__ char smem[70144];            // 34816 + 34816 + 512 (ldis)
    char* Abase = smem;
    char* Bbase = smem + 34816;
    float* ldis = (float*)(smem + 69632);

    const int tid = threadIdx.x;
    const int r0 = blockIdx.x * 128;

#pragma unroll
    for (int s = 0; s < 8; ++s) {
        int l = tid + s * 256;
        int row = l >> 4, q = l & 15;
        uint4 va = *(const uint4*)(Ab + (size_t)(r0 + row) * 64 + q * 4);
        *(uint4*)(Abase + row * 272 + q * 16) = va;
        uint4 vb = *(const uint4*)(Wt + (size_t)row * 64 + q * 4);
        *(uint4*)(Bbase + row * 272 + q * 16) = vb;
    }
    if (tid < 128) {
        int rr = r0 + tid;
        ldis[tid] = (rr < M) ? dis[rr] : 0.f;
    }
    __syncthreads();

    const int wv = tid >> 6, lane = tid & 63;
    const int quad = lane >> 4, mcol = lane & 15;

    // ---------------- GEMM1: acc1 = xab @ W1t^T ----------------
    f32x4 acc1[2][8];
#pragma unroll
    for (int rt = 0; rt < 2; ++rt)
#pragma unroll
        for (int ct = 0; ct < 8; ++ct) acc1[rt][ct] = (f32x4){0.f, 0.f, 0.f, 0.f};

#pragma unroll
    for (int ks = 0; ks < 4; ++ks) {
        bf16x8 a[2], b[8];
#pragma unroll
        for (int rt = 0; rt < 2; ++rt) {
            int row = wv * 32 + rt * 16 + mcol;
            a[rt] = *(const bf16x8*)(Abase + row * 272 + ks * 64 + quad * 16);
        }
#pragma unroll
        for (int ct = 0; ct < 8; ++ct) {
            int n = ct * 16 + mcol;
            b[ct] = *(const bf16x8*)(Bbase + n * 272 + ks * 64 + quad * 16);
        }
#pragma unroll
        for (int rt = 0; rt < 2; ++rt)
#pragma unroll
            for (int ct = 0; ct < 8; ++ct)
                acc1[rt][ct] = __builtin_amdgcn_mfma_f32_16x16x32_bf16(
                    a[rt], b[ct], acc1[rt][ct], 0, 0, 0);
    }
    __syncthreads();     // all waves done reading As (xab) and Bs (W1)

    // h (relu + bias, bf16) -> Bs region; W2 tile -> As region
    unsigned short* Hs = (unsigned short*)Bbase;     // pitch 136 ushorts
#pragma unroll
    for (int rt = 0; rt < 2; ++rt)
#pragma unroll
        for (int ct = 0; ct < 8; ++ct) {
            float bb = bias[ct * 16 + mcol];
#pragma unroll
            for (int r = 0; r < 4; ++r) {
                float v = acc1[rt][ct][r] + bb;
                v = v > 0.f ? v : 0.f;
                int orow = wv * 32 + rt * 16 + quad * 4 + r;
                Hs[orow * 136 + ct * 16 + mcol] = (unsigned short)bf16rn(v);
            }
        }
#pragma unroll
    for (int s = 0; s < 3; ++s) {
        int l = tid + s * 256;
        int row = l >> 4, q = l & 15;
        uint4 vb = *(const uint4*)(W2t + (size_t)row * 64 + q * 4);
        *(uint4*)(Abase + row * 272 + q * 16) = vb;
    }
    __syncthreads();

    // ---------------- GEMM2: acc2 = h @ W2t^T ----------------
    f32x4 acc2[2][3];
#pragma unroll
    for (int rt = 0; rt < 2; ++rt)
#pragma unroll
        for (int ct = 0; ct < 3; ++ct) acc2[rt][ct] = (f32x4){0.f, 0.f, 0.f, 0.f};

#pragma unroll
    for (int ks = 0; ks < 4; ++ks) {
        bf16x8 a[2], b[3];
#pragma unroll
        for (int rt = 0; rt < 2; ++rt) {
            int row = wv * 32 + rt * 16 + mcol;
            a[rt] = *(const bf16x8*)(Bbase + row * 272 + ks * 64 + quad * 16);
        }
#pragma unroll
        for (int ct = 0; ct < 3; ++ct) {
            int n = ct * 16 + mcol;
            b[ct] = *(const bf16x8*)(Abase + n * 272 + ks * 64 + quad * 16);
        }
#pragma unroll
        for (int rt = 0; rt < 2; ++rt)
#pragma unroll
            for (int ct = 0; ct < 3; ++ct)
                acc2[rt][ct] = __builtin_amdgcn_mfma_f32_16x16x32_bf16(
                    a[rt], b[ct], acc2[rt][ct], 0, 0, 0);
    }
    __syncthreads();

    // epilogue: scale by dis[row], pack bf16 rows at 56-ushort pitch (112 B)
    unsigned short* Zs = (unsigned short*)(Abase + 16384);  // above W2 (13056 B)
#pragma unroll
    for (int rt = 0; rt < 2; ++rt)
#pragma unroll
        for (int ct = 0; ct < 3; ++ct) {
#pragma unroll
            for (int r = 0; r < 4; ++r) {
                int orow = wv * 32 + rt * 16 + quad * 4 + r;
                float v = acc2[rt][ct][r] * ldis[orow];
                Zs[orow * 56 + ct * 16 + mcol] = (unsigned short)bf16rn(v);
            }
        }
    __syncthreads();

    if (tid < 128) {
        int rr = r0 + tid;
        if (rr < M) {
            const uint4* s4 = (const uint4*)(Abase + 16384 + tid * 112);
            uint4* d4 = (uint4*)(Zb + ((size_t)rr << 5));   // pitch 32 uints
#pragma unroll
            for (int q = 0; q < 5; ++q) d4[q] = s4[q];
        }
    }
}

// ---- gather layer 2: out[c] = b2 + dis[c] * (sum_r zb[r] + zb[c]) ---------
// Half-wave per edge stream; 16 edges in flight (8 per half).
// zb pitch = 32 uints (128 B): one aligned cache line per random row.
__global__ __launch_bounds__(256) void k_gather2(const unsigned* __restrict__ zb,
                                                 const int2* __restrict__ rpse,
                                                 const int* __restrict__ pair,
                                                 const float* __restrict__ dis,
                                                 const float* __restrict__ b2,
                                                 float* __restrict__ out, int N) {
    int gw = (blockIdx.x * 256 + threadIdx.x) >> 6;
    int lane = threadIdx.x & 63;
    if (gw >= N) return;
    int sub = lane >> 5;
    int sl  = lane & 31;
    int f   = (sl < 20) ? sl : 19;

    float2 acc = make_float2(0.f, 0.f);
    float dv = dis[gw];
    if (sub == 0) {                       // self term (rows pre-scaled by dis)
        unsigned u = zb[((size_t)gw << 5) + f];
        acc.x = bf_lo(u); acc.y = bf_hi(u);
    }

    int2 rp = rpse[gw];
    int j = rp.x, je = rp.y;
    for (; j + 15 < je; j += 16) {
        int rA = pair[j + sub];
        int rB = pair[j + 2 + sub];
        int rC = pair[j + 4 + sub];
        int rD = pair[j + 6 + sub];
        int rE = pair[j + 8 + sub];
        int rF = pair[j + 10 + sub];
        int rG = pair[j + 12 + sub];
        int rH = pair[j + 14 + sub];
        unsigned uA = zb[((size_t)rA << 5) + f];
        unsigned uB = zb[((size_t)rB << 5) + f];
        unsigned uC = zb[((size_t)rC << 5) + f];
        unsigned uD = zb[((size_t)rD << 5) + f];
        unsigned uE = zb[((size_t)rE << 5) + f];
        unsigned uF = zb[((size_t)rF << 5) + f];
        unsigned uG = zb[((size_t)rG << 5) + f];
        unsigned uH = zb[((size_t)rH << 5) + f];
        acc.x += bf_lo(uA); acc.y += bf_hi(uA);
        acc.x += bf_lo(uB); acc.y += bf_hi(uB);
        acc.x += bf_lo(uC); acc.y += bf_hi(uC);
        acc.x += bf_lo(uD); acc.y += bf_hi(uD);
        acc.x += bf_lo(uE); acc.y += bf_hi(uE);
        acc.x += bf_lo(uF); acc.y += bf_hi(uF);
        acc.x += bf_lo(uG); acc.y += bf_hi(uG);
        acc.x += bf_lo(uH); acc.y += bf_hi(uH);
    }
    for (; j + 7 < je; j += 8) {
        int rA = pair[j + sub];
        int rB = pair[j + 2 + sub];
        int rC = pair[j + 4 + sub];
        int rD = pair[j + 6 + sub];
        unsigned uA = zb[((size_t)rA << 5) + f];
        unsigned uB = zb[((size_t)rB << 5) + f];
        unsigned uC = zb[((size_t)rC << 5) + f];
        unsigned uD = zb[((size_t)rD << 5) + f];
        acc.x += bf_lo(uA); acc.y += bf_hi(uA);
        acc.x += bf_lo(uB); acc.y += bf_hi(uB);
        acc.x += bf_lo(uC); acc.y += bf_hi(uC);
        acc.x += bf_lo(uD); acc.y += bf_hi(uD);
    }
    for (; j + 3 < je; j += 4) {
        int rA = pair[j + sub];
        int rB = pair[j + 2 + sub];
        unsigned uA = zb[((size_t)rA << 5) + f];
        unsigned uB = zb[((size_t)rB << 5) + f];
        acc.x += bf_lo(uA); acc.y += bf_hi(uA);
        acc.x += bf_lo(uB); acc.y += bf_hi(uB);
    }
    for (; j + 1 < je; j += 2) {
        unsigned u = zb[((size_t)pair[j + sub] << 5) + f];
        acc.x += bf_lo(u); acc.y += bf_hi(u);
    }
    if (j < je && sub == 0) {
        unsigned u = zb[((size_t)pair[j] << 5) + f];
        acc.x += bf_lo(u); acc.y += bf_hi(u);
    }

    float bx = __shfl(acc.x, sl + 32, 64);
    float by = __shfl(acc.y, sl + 32, 64);
    if (sub == 0 && sl < 20) {
        float2 bias = ((const float2*)b2)[sl];
        float2 res = make_float2((acc.x + bx) * dv + bias.x,
                                 (acc.y + by) * dv + bias.y);
        ((float2*)(out + (size_t)gw * 40))[sl] = res;
    }
}

// ---------------------------------------------------------------------------
extern "C" void kernel_launch(void* const* d_in, const int* in_sizes, int n_in,
                              void* d_out, int out_size, void* d_ws, size_t ws_size,
                              hipStream_t stream) {
    const float* x  = (const float*)d_in[0];
    const int*   ei = (const int*)d_in[1];
    const float* W1 = (const float*)d_in[2];
    const float* b1 = (const float*)d_in[3];
    const float* W2 = (const float*)d_in[4];
    const float* b2 = (const float*)d_in[5];
    float* out = (float*)d_out;

    const int N = in_sizes[0] / 128;
    const int E = in_sizes[1] / 2;
    const int* row = ei;        // sources
    const int* col = ei + E;    // targets

    const int Np = (N + 255) & ~255;
    const int nbuck = (N + (1 << FB_SHIFT) - 1) >> FB_SHIFT;   // <= 256
    const int nEB = (E + 4095) / 4096;

    // workspace layout (4-byte units), ~82 MB total
    int*      bcur   = (int*)d_ws;                       // 256
    int2*     rpse   = (int2*)(bcur + 256);              // Np int2 (2*Np ints)
    float*    dis    = (float*)(rpse + Np);              // Np
    unsigned* Wt     = (unsigned*)(dis + Np);            // 8192 (W1t bf16)
    unsigned* W2t    = Wt + 8192;                        // 3072 (W2t bf16, 48 rows)
    int*      pair   = (int*)(W2t + 3072);               // 256<<14 slabbed
    unsigned* xbs    = (unsigned*)(pair + ((size_t)256 << SLAB_SHIFT)); // N*64 sliced
    unsigned* xab    = xbs + (size_t)N * 64;             // N*64 (bf16 A*x, row-major)
    unsigned* zb     = xab + (size_t)N * 64;             // N*32 (bf16 z*dis, padded)
    unsigned* bins   = (unsigned*)xab;  // alias: slabbed, dead before gather1

    // slab-bucketed CSC build (no global histogram/scan needed)
    hipMemsetAsync(bcur, 0, 256 * sizeof(int), stream);
    k_binfill<<<nEB + 22, 512, 0, stream>>>(row, col, bcur, bins, E, nEB,
                                            W1, W2, Wt, W2t);
    k_fill2<<<nbuck, 1024, 0, stream>>>(bins, bcur, rpse, dis, pair, N);

    // x conversion into sliced layout (full grid, reads dis)
    k_cvtx<<<(N * 32 + 255) / 256, 256, 0, stream>>>(x, dis, xbs, N);

    // layer 1 gather, feature-sliced: xab = bf16(A x)
    k_gather1s<<<((N + 3) / 4) * 8, 256, 0, stream>>>(xbs, rpse, pair, dis, xab, N);

    // fused GEMMs: zb = bf16((relu(xab@W1+b1) @ W2) * dis)   [MFMA]
    k_gemm12<<<(N + 127) / 128, 256, 0, stream>>>(xab, Wt, W2t, b1, dis, zb, N);

    // layer 2 gather: out = b2 + dis*(sum zb)
    k_gather2<<<(N + 3) / 4, 256, 0, stream>>>(zb, rpse, pair, dis, b2, out, N);
}

// Round 10
// 358.054 us; speedup vs baseline: 1.2249x; 1.2249x over previous
//
#include <hip/hip_runtime.h>
#include <hip/hip_bf16.h>

// ---------------------------------------------------------------------------
// 2-layer GCN, atomic-free CSC gather, bf16 payloads + bf16 MFMA GEMMs.
// dis[] is folded into the gathered payloads (xb = x*dis, zb = z*dis), so
// edge records are source-index-only (4 B). Aggregation at target c:
//   A·v|_c = dis[c] * (sum_r payload[r] + payload[c])
// Layer 1: h = relu((A x) @ W1 + b1)   [reassociated]
// Layer 2: out = A (h @ W2) + b2
//
// R8: SLAB buckets — k_bcount/k_bscanw deleted; fill2 emits int2 rpse.
// R9: FEATURE-SLICED gather1: xbs [8][N][32B], slice = blockIdx%8 -> XCD
// L2 holds only its 3.2MB slice. VALIDATED: FETCH 190->65MB. But MLP
// collapsed (8 edges/inst x deg 16 = ~2 loads in flight) -> 249us.
// R10: multi-node sliced gather (k_gather1m): each wave processes 4 nodes
// concurrently -> up to 4 independent loads in flight per iteration;
// wave-uniform branches; one-inst self-term and 4-node packed store.
// ---------------------------------------------------------------------------

#define FB_SHIFT 9              // 512 nodes per bucket; r<2^17 packs with c_local
#define SLAB_SHIFT 14           // 16384 edge slots per bucket slab (~1.9x max)

__device__ __forceinline__ unsigned bf16rn(float f) {
    unsigned x = __float_as_uint(f);
    unsigned r = ((x >> 16) & 1u) + 0x7fffu;   // RNE
    return (x + r) >> 16;
}
__device__ __forceinline__ float bf_lo(unsigned u) { return __uint_as_float(u << 16); }
__device__ __forceinline__ float bf_hi(unsigned u) { return __uint_as_float(u & 0xffff0000u); }

typedef __bf16 bf16x8 __attribute__((ext_vector_type(8)));
typedef float  f32x4  __attribute__((ext_vector_type(4)));

// ---- multisplit: bin edges by target bucket into fixed slabs --------------
__global__ __launch_bounds__(512) void k_binfill(const int* __restrict__ row,
                                                 const int* __restrict__ col,
                                                 int* __restrict__ bcur,
                                                 unsigned* __restrict__ bins, int E,
                                                 int nEB,
                                                 const float* __restrict__ W1,
                                                 const float* __restrict__ W2,
                                                 unsigned* __restrict__ Wt,
                                                 unsigned* __restrict__ W2t) {
    const int tid = threadIdx.x;

    if (blockIdx.x >= nEB) {            // ---- W-conversion tail blocks ----
        int w = (blockIdx.x - nEB) * 512 + tid;   // 0..11263
        if (w < 8192) {
            int n = w >> 6, kk = (w & 63) * 2;
            unsigned lo = bf16rn(W1[(size_t)kk * 128 + n]);
            unsigned hi = bf16rn(W1[(size_t)(kk + 1) * 128 + n]);
            Wt[w] = lo | (hi << 16);
        } else if (w < 8192 + 3072) {
            int u = w - 8192;
            int n = u >> 6, kk = (u & 63) * 2;
            unsigned lo = 0, hi = 0;
            if (n < 40) {
                lo = bf16rn(W2[(size_t)kk * 40 + n]);
                hi = bf16rn(W2[(size_t)(kk + 1) * 40 + n]);
            }
            W2t[u] = lo | (hi << 16);
        }
        return;
    }

    __shared__ int hist[256];
    __shared__ int scn[256];
    __shared__ int gbase[256];
    __shared__ int rcnt[256];
    __shared__ unsigned stage[4096];
    __shared__ unsigned char bkts[4096];

    const int base = blockIdx.x * 4096;

    if (tid < 256) { hist[tid] = 0; rcnt[tid] = 0; }
    __syncthreads();

    unsigned mypk[8];
    int      myb[8];
#pragma unroll
    for (int k = 0; k < 8; ++k) {
        int e = base + k * 512 + tid;
        if (e < E) {
            int r = row[e], c = col[e];
            int b = c >> FB_SHIFT;
            mypk[k] = ((unsigned)r << FB_SHIFT) | (unsigned)(c & ((1 << FB_SHIFT) - 1));
            myb[k] = b;
            atomicAdd(&hist[b], 1);
        } else {
            myb[k] = -1;
        }
    }
    __syncthreads();

    int v = 0;
    if (tid < 256) { v = hist[tid]; scn[tid] = v; }
    __syncthreads();
#pragma unroll
    for (int off = 1; off < 256; off <<= 1) {
        int t = (tid >= off && tid < 256) ? scn[tid - off] : 0;
        __syncthreads();
        if (tid < 256) scn[tid] += t;
        __syncthreads();
    }
    if (tid < 256) {
        int excl = scn[tid] - v;
        scn[tid] = excl;
    }
    __syncthreads();

#pragma unroll
    for (int k = 0; k < 8; ++k) {
        int b = myb[k];
        if (b >= 0) {
            int slot = scn[b] + atomicAdd(&rcnt[b], 1);
            stage[slot] = mypk[k];
            bkts[slot] = (unsigned char)b;
        }
    }

    if (tid < 256 && hist[tid] > 0) gbase[tid] = atomicAdd(&bcur[tid], hist[tid]);
    __syncthreads();

    int total = scn[255] + hist[255];
    const int cap = 1 << SLAB_SHIFT;
    for (int s = tid; s < total; s += 512) {
        unsigned u = stage[s];
        int b = bkts[s];
        int off = gbase[b] + (s - scn[b]);
        if (off < cap)                              // clamp (pathological only)
            bins[((size_t)b << SLAB_SHIFT) + off] = u;
    }
}

// ---- per-bucket: degree count + local scan + scatter; emits rpse + dis ----
__global__ __launch_bounds__(1024) void k_fill2(const unsigned* __restrict__ bins,
                                                const int* __restrict__ bcur,
                                                int2* __restrict__ rpse,
                                                float* __restrict__ dis,
                                                int* __restrict__ pair, int N) {
    __shared__ int cnt[512];
    __shared__ int lcur[512];
    __shared__ int ssum[256];
    const int tid = threadIdx.x;
    const int b = blockIdx.x;
    const int n0 = b << FB_SHIFT;
    const int start = b << SLAB_SHIFT;
    int count = bcur[b];
    if (count > (1 << SLAB_SHIFT)) count = 1 << SLAB_SHIFT;
    const int end = start + count;

    if (tid < 512) cnt[tid] = 0;
    __syncthreads();

    for (int i = start + tid; i < end; i += 1024)
        atomicAdd(&cnt[bins[i] & ((1 << FB_SHIFT) - 1)], 1);
    __syncthreads();

    int c0 = 0, c1 = 0, vsum = 0;
    if (tid < 256) {
        c0 = cnt[2 * tid]; c1 = cnt[2 * tid + 1];
        vsum = c0 + c1;
        ssum[tid] = vsum;
    }
    __syncthreads();
#pragma unroll
    for (int off = 1; off < 256; off <<= 1) {
        int u = (tid >= off && tid < 256) ? ssum[tid - off] : 0;
        __syncthreads();
        if (tid < 256) ssum[tid] += u;
        __syncthreads();
    }
    if (tid < 256) {
        int e0 = start + ssum[tid] - vsum;
        int e1 = e0 + c0;
        lcur[2 * tid] = e0;
        lcur[2 * tid + 1] = e1;
        int node0 = n0 + 2 * tid;
        int node1 = node0 + 1;
        if (node0 < N) {
            rpse[node0] = make_int2(e0, e1);
            dis[node0] = rsqrtf((float)(c0 + 1));   // +1 self-loop
        }
        if (node1 < N) {
            rpse[node1] = make_int2(e1, e1 + c1);
            dis[node1] = rsqrtf((float)(c1 + 1));
        }
    }
    __syncthreads();

    for (int i = start + tid; i < end; i += 1024) {
        unsigned u = bins[i];
        int pos = atomicAdd(&lcur[u & ((1 << FB_SHIFT) - 1)], 1);
        pair[pos] = (int)(u >> FB_SHIFT);
    }
}

// ---- x -> xbs (slice-major [8][N][8 uints]) = bf16x2(x * dis) -------------
__global__ __launch_bounds__(256) void k_cvtx(const float* __restrict__ x,
                                              const float* __restrict__ dis,
                                              unsigned* __restrict__ xbs, int N) {
    int i = blockIdx.x * 256 + threadIdx.x;
    if (i >= N * 32) return;
    int n = i >> 5;                 // node
    int k2 = (i & 31) * 2;          // uint index within row (even)
    float4 v = ((const float4*)x)[i];
    float d = dis[n];
    uint2 o;
    o.x = bf16rn(v.x * d) | (bf16rn(v.y * d) << 16);
    o.y = bf16rn(v.z * d) | (bf16rn(v.w * d) << 16);
    int s = k2 >> 3, f = k2 & 7;    // slice, uint-in-slice (f even, f+1 same slice)
    *(uint2*)(xbs + ((size_t)s * N + n) * 8 + f) = o;
}

// ---- gather layer 1, feature-sliced, 4 nodes per wave ---------------------
// slice = blockIdx%8 (round-robin block->XCD, validated by R9's FETCH drop).
// Wave = 8 edge-groups x 8 feature-lanes; 4 nodes concurrently -> up to 4
// independent vmem loads in flight per while-iteration (wave-uniform guards).
__global__ __launch_bounds__(256) void k_gather1m(const unsigned* __restrict__ xbs,
                                                  const int2* __restrict__ rpse,
                                                  const int* __restrict__ pair,
                                                  const float* __restrict__ dis,
                                                  unsigned* __restrict__ xab, int N) {
    const int bid = blockIdx.x;
    const int s = bid & 7;
    const int wv = threadIdx.x >> 6;
    const int n0 = (bid >> 3) * 16 + wv * 4;    // 4 nodes per wave
    if (n0 >= N) return;
    const int lane = threadIdx.x & 63;
    const int eg = lane >> 3;       // edge group 0..7
    const int fl = lane & 7;        // uint within 32B slice

    const unsigned* base = xbs + (size_t)s * N * 8;

    const int nA = n0, nB = n0 + 1, nC = n0 + 2, nD = n0 + 3;
    int2 rA = rpse[nA];
    int2 rB = (nB < N) ? rpse[nB] : make_int2(0, 0);
    int2 rC = (nC < N) ? rpse[nC] : make_int2(0, 0);
    int2 rD = (nD < N) ? rpse[nD] : make_int2(0, 0);
    int jA = rA.x, eA = rA.y;
    int jB = rB.x, eB = rB.y;
    int jC = rC.x, eC = rC.y;
    int jD = rD.x, eD = rD.y;

    float axA = 0.f, ayA = 0.f, axB = 0.f, ayB = 0.f;
    float axC = 0.f, ayC = 0.f, axD = 0.f, ayD = 0.f;

    // self terms: lanes eg==m load node m's 32B slice (one inst, 4 segments)
    if (eg < 4) {
        int nm = n0 + eg;
        if (nm < N) {
            unsigned u = base[(size_t)nm * 8 + fl];
            float lx = bf_lo(u), ly = bf_hi(u);
            if (eg == 0)      { axA = lx; ayA = ly; }
            else if (eg == 1) { axB = lx; ayB = ly; }
            else if (eg == 2) { axC = lx; ayC = ly; }
            else              { axD = lx; ayD = ly; }
        }
    }

    // main loop: up to 4 independent 8-edge loads in flight
    while ((jA + 7 < eA) || (jB + 7 < eB) || (jC + 7 < eC) || (jD + 7 < eD)) {
        unsigned u0 = 0, u1 = 0, u2 = 0, u3 = 0;
        if (jA + 7 < eA) { int r = pair[jA + eg]; u0 = base[(size_t)r * 8 + fl]; jA += 8; }
        if (jB + 7 < eB) { int r = pair[jB + eg]; u1 = base[(size_t)r * 8 + fl]; jB += 8; }
        if (jC + 7 < eC) { int r = pair[jC + eg]; u2 = base[(size_t)r * 8 + fl]; jC += 8; }
        if (jD + 7 < eD) { int r = pair[jD + eg]; u3 = base[(size_t)r * 8 + fl]; jD += 8; }
        axA += bf_lo(u0); ayA += bf_hi(u0);
        axB += bf_lo(u1); ayB += bf_hi(u1);
        axC += bf_lo(u2); ayC += bf_hi(u2);
        axD += bf_lo(u3); ayD += bf_hi(u3);
    }
    // tails (<8 edges each), per-lane predicated
    if (jA + eg < eA) { int r = pair[jA + eg]; unsigned u = base[(size_t)r * 8 + fl]; axA += bf_lo(u); ayA += bf_hi(u); }
    if (jB + eg < eB) { int r = pair[jB + eg]; unsigned u = base[(size_t)r * 8 + fl]; axB += bf_lo(u); ayB += bf_hi(u); }
    if (jC + eg < eC) { int r = pair[jC + eg]; unsigned u = base[(size_t)r * 8 + fl]; axC += bf_lo(u); ayC += bf_hi(u); }
    if (jD + eg < eD) { int r = pair[jD + eg]; unsigned u = base[(size_t)r * 8 + fl]; axD += bf_lo(u); ayD += bf_hi(u); }

    // reduce across the 8 edge-groups (stride 8, 16, 32)
    axA += __shfl_xor(axA, 8, 64);  ayA += __shfl_xor(ayA, 8, 64);
    axA += __shfl_xor(axA, 16, 64); ayA += __shfl_xor(ayA, 16, 64);
    axA += __shfl_xor(axA, 32, 64); ayA += __shfl_xor(ayA, 32, 64);
    axB += __shfl_xor(axB, 8, 64);  ayB += __shfl_xor(ayB, 8, 64);
    axB += __shfl_xor(axB, 16, 64); ayB += __shfl_xor(ayB, 16, 64);
    axB += __shfl_xor(axB, 32, 64); ayB += __shfl_xor(ayB, 32, 64);
    axC += __shfl_xor(axC, 8, 64);  ayC += __shfl_xor(ayC, 8, 64);
    axC += __shfl_xor(axC, 16, 64); ayC += __shfl_xor(ayC, 16, 64);
    axC += __shfl_xor(axC, 32, 64); ayC += __shfl_xor(ayC, 32, 64);
    axD += __shfl_xor(axD, 8, 64);  ayD += __shfl_xor(ayD, 8, 64);
    axD += __shfl_xor(axD, 16, 64); ayD += __shfl_xor(ayD, 16, 64);
    axD += __shfl_xor(axD, 32, 64); ayD += __shfl_xor(ayD, 32, 64);

    // store: lanes eg<4 write node (n0+eg)'s 32B of the row-major xab
    if (eg < 4) {
        int nm = n0 + eg;
        if (nm < N) {
            float vx = (eg == 0) ? axA : (eg == 1) ? axB : (eg == 2) ? axC : axD;
            float vy = (eg == 0) ? ayA : (eg == 1) ? ayB : (eg == 2) ? ayC : ayD;
            float dv = dis[nm];
            xab[(size_t)nm * 64 + s * 8 + fl] =
                bf16rn(dv * vx) | (bf16rn(dv * vy) << 16);
        }
    }
}

// ---- fused GEMM1+GEMM2 (MFMA bf16) ----------------------------------------
// h = relu(xab @ W1t^T + b1)  (h kept in LDS, never hits global)
// Zb[M, pitch 32] = bf16( (h @ W2t^T) * dis[row] )  (20 uints used, 12 pad)
__global__ __launch_bounds__(256) void k_gemm12(const unsigned* __restrict__ Ab,
                                                const unsigned* __restrict__ Wt,
                                                const unsigned* __restrict__ W2t,
                                                const float* __restrict__ bias,
                                                const float* __restrict__ dis,
                                                unsigned* __restrict__ Zb, int M) {
    __shared__ char smem[70144];            // 34816 + 34816 + 512 (ldis)
    char* Abase = smem;
    char* Bbase = smem + 34816;
    float* ldis = (float*)(smem + 69632);

    const int tid = threadIdx.x;
    const int r0 = blockIdx.x * 128;

#pragma unroll
    for (int s = 0; s < 8; ++s) {
        int l = tid + s * 256;
        int row = l >> 4, q = l & 15;
        uint4 va = *(const uint4*)(Ab + (size_t)(r0 + row) * 64 + q * 4);
        *(uint4*)(Abase + row * 272 + q * 16) = va;
        uint4 vb = *(const uint4*)(Wt + (size_t)row * 64 + q * 4);
        *(uint4*)(Bbase + row * 272 + q * 16) = vb;
    }
    if (tid < 128) {
        int rr = r0 + tid;
        ldis[tid] = (rr < M) ? dis[rr] : 0.f;
    }
    __syncthreads();

    const int wv = tid >> 6, lane = tid & 63;
    const int quad = lane >> 4, mcol = lane & 15;

    // ---------------- GEMM1: acc1 = xab @ W1t^T ----------------
    f32x4 acc1[2][8];
#pragma unroll
    for (int rt = 0; rt < 2; ++rt)
#pragma unroll
        for (int ct = 0; ct < 8; ++ct) acc1[rt][ct] = (f32x4){0.f, 0.f, 0.f, 0.f};

#pragma unroll
    for (int ks = 0; ks < 4; ++ks) {
        bf16x8 a[2], b[8];
#pragma unroll
        for (int rt = 0; rt < 2; ++rt) {
            int row = wv * 32 + rt * 16 + mcol;
            a[rt] = *(const bf16x8*)(Abase + row * 272 + ks * 64 + quad * 16);
        }
#pragma unroll
        for (int ct = 0; ct < 8; ++ct) {
            int n = ct * 16 + mcol;
            b[ct] = *(const bf16x8*)(Bbase + n * 272 + ks * 64 + quad * 16);
        }
#pragma unroll
        for (int rt = 0; rt < 2; ++rt)
#pragma unroll
            for (int ct = 0; ct < 8; ++ct)
                acc1[rt][ct] = __builtin_amdgcn_mfma_f32_16x16x32_bf16(
                    a[rt], b[ct], acc1[rt][ct], 0, 0, 0);
    }
    __syncthreads();     // all waves done reading As (xab) and Bs (W1)

    // h (relu + bias, bf16) -> Bs region; W2 tile -> As region
    unsigned short* Hs = (unsigned short*)Bbase;     // pitch 136 ushorts
#pragma unroll
    for (int rt = 0; rt < 2; ++rt)
#pragma unroll
        for (int ct = 0; ct < 8; ++ct) {
            float bb = bias[ct * 16 + mcol];
#pragma unroll
            for (int r = 0; r < 4; ++r) {
                float v = acc1[rt][ct][r] + bb;
                v = v > 0.f ? v : 0.f;
                int orow = wv * 32 + rt * 16 + quad * 4 + r;
                Hs[orow * 136 + ct * 16 + mcol] = (unsigned short)bf16rn(v);
            }
        }
#pragma unroll
    for (int s = 0; s < 3; ++s) {
        int l = tid + s * 256;
        int row = l >> 4, q = l & 15;
        uint4 vb = *(const uint4*)(W2t + (size_t)row * 64 + q * 4);
        *(uint4*)(Abase + row * 272 + q * 16) = vb;
    }
    __syncthreads();

    // ---------------- GEMM2: acc2 = h @ W2t^T ----------------
    f32x4 acc2[2][3];
#pragma unroll
    for (int rt = 0; rt < 2; ++rt)
#pragma unroll
        for (int ct = 0; ct < 3; ++ct) acc2[rt][ct] = (f32x4){0.f, 0.f, 0.f, 0.f};

#pragma unroll
    for (int ks = 0; ks < 4; ++ks) {
        bf16x8 a[2], b[3];
#pragma unroll
        for (int rt = 0; rt < 2; ++rt) {
            int row = wv * 32 + rt * 16 + mcol;
            a[rt] = *(const bf16x8*)(Bbase + row * 272 + ks * 64 + quad * 16);
        }
#pragma unroll
        for (int ct = 0; ct < 3; ++ct) {
            int n = ct * 16 + mcol;
            b[ct] = *(const bf16x8*)(Abase + n * 272 + ks * 64 + quad * 16);
        }
#pragma unroll
        for (int rt = 0; rt < 2; ++rt)
#pragma unroll
            for (int ct = 0; ct < 3; ++ct)
                acc2[rt][ct] = __builtin_amdgcn_mfma_f32_16x16x32_bf16(
                    a[rt], b[ct], acc2[rt][ct], 0, 0, 0);
    }
    __syncthreads();

    // epilogue: scale by dis[row], pack bf16 rows at 56-ushort pitch (112 B)
    unsigned short* Zs = (unsigned short*)(Abase + 16384);  // above W2 (13056 B)
#pragma unroll
    for (int rt = 0; rt < 2; ++rt)
#pragma unroll
        for (int ct = 0; ct < 3; ++ct) {
#pragma unroll
            for (int r = 0; r < 4; ++r) {
                int orow = wv * 32 + rt * 16 + quad * 4 + r;
                float v = acc2[rt][ct][r] * ldis[orow];
                Zs[orow * 56 + ct * 16 + mcol] = (unsigned short)bf16rn(v);
            }
        }
    __syncthreads();

    if (tid < 128) {
        int rr = r0 + tid;
        if (rr < M) {
            const uint4* s4 = (const uint4*)(Abase + 16384 + tid * 112);
            uint4* d4 = (uint4*)(Zb + ((size_t)rr << 5));   // pitch 32 uints
#pragma unroll
            for (int q = 0; q < 5; ++q) d4[q] = s4[q];
        }
    }
}

// ---- gather layer 2: out[c] = b2 + dis[c] * (sum_r zb[r] + zb[c]) ---------
// Half-wave per edge stream; 16 edges in flight (8 per half).
// zb pitch = 32 uints (128 B): one aligned cache line per random row.
__global__ __launch_bounds__(256) void k_gather2(const unsigned* __restrict__ zb,
                                                 const int2* __restrict__ rpse,
                                                 const int* __restrict__ pair,
                                                 const float* __restrict__ dis,
                                                 const float* __restrict__ b2,
                                                 float* __restrict__ out, int N) {
    int gw = (blockIdx.x * 256 + threadIdx.x) >> 6;
    int lane = threadIdx.x & 63;
    if (gw >= N) return;
    int sub = lane >> 5;
    int sl  = lane & 31;
    int f   = (sl < 20) ? sl : 19;

    float2 acc = make_float2(0.f, 0.f);
    float dv = dis[gw];
    if (sub == 0) {                       // self term (rows pre-scaled by dis)
        unsigned u = zb[((size_t)gw << 5) + f];
        acc.x = bf_lo(u); acc.y = bf_hi(u);
    }

    int2 rp = rpse[gw];
    int j = rp.x, je = rp.y;
    for (; j + 15 < je; j += 16) {
        int rA = pair[j + sub];
        int rB = pair[j + 2 + sub];
        int rC = pair[j + 4 + sub];
        int rD = pair[j + 6 + sub];
        int rE = pair[j + 8 + sub];
        int rF = pair[j + 10 + sub];
        int rG = pair[j + 12 + sub];
        int rH = pair[j + 14 + sub];
        unsigned uA = zb[((size_t)rA << 5) + f];
        unsigned uB = zb[((size_t)rB << 5) + f];
        unsigned uC = zb[((size_t)rC << 5) + f];
        unsigned uD = zb[((size_t)rD << 5) + f];
        unsigned uE = zb[((size_t)rE << 5) + f];
        unsigned uF = zb[((size_t)rF << 5) + f];
        unsigned uG = zb[((size_t)rG << 5) + f];
        unsigned uH = zb[((size_t)rH << 5) + f];
        acc.x += bf_lo(uA); acc.y += bf_hi(uA);
        acc.x += bf_lo(uB); acc.y += bf_hi(uB);
        acc.x += bf_lo(uC); acc.y += bf_hi(uC);
        acc.x += bf_lo(uD); acc.y += bf_hi(uD);
        acc.x += bf_lo(uE); acc.y += bf_hi(uE);
        acc.x += bf_lo(uF); acc.y += bf_hi(uF);
        acc.x += bf_lo(uG); acc.y += bf_hi(uG);
        acc.x += bf_lo(uH); acc.y += bf_hi(uH);
    }
    for (; j + 7 < je; j += 8) {
        int rA = pair[j + sub];
        int rB = pair[j + 2 + sub];
        int rC = pair[j + 4 + sub];
        int rD = pair[j + 6 + sub];
        unsigned uA = zb[((size_t)rA << 5) + f];
        unsigned uB = zb[((size_t)rB << 5) + f];
        unsigned uC = zb[((size_t)rC << 5) + f];
        unsigned uD = zb[((size_t)rD << 5) + f];
        acc.x += bf_lo(uA); acc.y += bf_hi(uA);
        acc.x += bf_lo(uB); acc.y += bf_hi(uB);
        acc.x += bf_lo(uC); acc.y += bf_hi(uC);
        acc.x += bf_lo(uD); acc.y += bf_hi(uD);
    }
    for (; j + 3 < je; j += 4) {
        int rA = pair[j + sub];
        int rB = pair[j + 2 + sub];
        unsigned uA = zb[((size_t)rA << 5) + f];
        unsigned uB = zb[((size_t)rB << 5) + f];
        acc.x += bf_lo(uA); acc.y += bf_hi(uA);
        acc.x += bf_lo(uB); acc.y += bf_hi(uB);
    }
    for (; j + 1 < je; j += 2) {
        unsigned u = zb[((size_t)pair[j + sub] << 5) + f];
        acc.x += bf_lo(u); acc.y += bf_hi(u);
    }
    if (j < je && sub == 0) {
        unsigned u = zb[((size_t)pair[j] << 5) + f];
        acc.x += bf_lo(u); acc.y += bf_hi(u);
    }

    float bx = __shfl(acc.x, sl + 32, 64);
    float by = __shfl(acc.y, sl + 32, 64);
    if (sub == 0 && sl < 20) {
        float2 bias = ((const float2*)b2)[sl];
        float2 res = make_float2((acc.x + bx) * dv + bias.x,
                                 (acc.y + by) * dv + bias.y);
        ((float2*)(out + (size_t)gw * 40))[sl] = res;
    }
}

// ---------------------------------------------------------------------------
extern "C" void kernel_launch(void* const* d_in, const int* in_sizes, int n_in,
                              void* d_out, int out_size, void* d_ws, size_t ws_size,
                              hipStream_t stream) {
    const float* x  = (const float*)d_in[0];
    const int*   ei = (const int*)d_in[1];
    const float* W1 = (const float*)d_in[2];
    const float* b1 = (const float*)d_in[3];
    const float* W2 = (const float*)d_in[4];
    const float* b2 = (const float*)d_in[5];
    float* out = (float*)d_out;

    const int N = in_sizes[0] / 128;
    const int E = in_sizes[1] / 2;
    const int* row = ei;        // sources
    const int* col = ei + E;    // targets

    const int Np = (N + 255) & ~255;
    const int nbuck = (N + (1 << FB_SHIFT) - 1) >> FB_SHIFT;   // <= 256
    const int nEB = (E + 4095) / 4096;

    // workspace layout (4-byte units), ~82 MB total
    int*      bcur   = (int*)d_ws;                       // 256
    int2*     rpse   = (int2*)(bcur + 256);              // Np int2 (2*Np ints)
    float*    dis    = (float*)(rpse + Np);              // Np
    unsigned* Wt     = (unsigned*)(dis + Np);            // 8192 (W1t bf16)
    unsigned* W2t    = Wt + 8192;                        // 3072 (W2t bf16, 48 rows)
    int*      pair   = (int*)(W2t + 3072);               // 256<<14 slabbed
    unsigned* xbs    = (unsigned*)(pair + ((size_t)256 << SLAB_SHIFT)); // N*64 sliced
    unsigned* xab    = xbs + (size_t)N * 64;             // N*64 (bf16 A*x, row-major)
    unsigned* zb     = xab + (size_t)N * 64;             // N*32 (bf16 z*dis, padded)
    unsigned* bins   = (unsigned*)xab;  // alias: slabbed, dead before gather1

    // slab-bucketed CSC build (no global histogram/scan needed)
    hipMemsetAsync(bcur, 0, 256 * sizeof(int), stream);
    k_binfill<<<nEB + 22, 512, 0, stream>>>(row, col, bcur, bins, E, nEB,
                                            W1, W2, Wt, W2t);
    k_fill2<<<nbuck, 1024, 0, stream>>>(bins, bcur, rpse, dis, pair, N);

    // x conversion into sliced layout (full grid, reads dis)
    k_cvtx<<<(N * 32 + 255) / 256, 256, 0, stream>>>(x, dis, xbs, N);

    // layer 1 gather, feature-sliced, 4 nodes/wave: xab = bf16(A x)
    k_gather1m<<<((N + 15) / 16) * 8, 256, 0, stream>>>(xbs, rpse, pair, dis, xab, N);

    // fused GEMMs: zb = bf16((relu(xab@W1+b1) @ W2) * dis)   [MFMA]
    k_gemm12<<<(N + 127) / 128, 256, 0, stream>>>(xab, Wt, W2t, b1, dis, zb, N);

    // layer 2 gather: out = b2 + dis*(sum zb)
    k_gather2<<<(N + 3) / 4, 256, 0, stream>>>(zb, rpse, pair, dis, b2, out, N);
}

// Round 11
// 292.723 us; speedup vs baseline: 1.4983x; 1.2232x over previous
//
#include <hip/hip_runtime.h>
#include <hip/hip_bf16.h>

// ---------------------------------------------------------------------------
// 2-layer GCN, atomic-free CSC gather, bf16 payloads + bf16 MFMA GEMMs.
// dis[] is folded into the gathered payloads (xb = x*dis, zb = z*dis), so
// edge records are source-index-only (4 B). Aggregation at target c:
//   A·v|_c = dis[c] * (sum_r payload[r] + payload[c])
// Layer 1: h = relu((A x) @ W1 + b1)   [reassociated]
// Layer 2: out = A (h @ W2) + b2
//
// R8: SLAB buckets — k_bcount/k_bscanw deleted; fill2 emits int2 rpse.
// R9/R10: 8x32B feature-slicing cut FETCH 190->65MB but 32B granules cut
// L2 delivery 6.5->1.6-2.5 TB/s (dur 63->249/167us). Lesson: gather1 is
// L2-fill-path bound (~3 TB/s); granule must stay >= 128B.
// R11: TWO 128B slices (xbs2 [2][N][128B], slice = blockIdx&1 -> XCD
// parity). Per-XCD compulsory ~12.6MB x8 + 2x pair = ~113MB fetch at
// full 128B granule. Wave = R2's proven paired-half-wave body (neutral
// on row-major): each 32-lane half covers a slice row, 16 edges in
// flight, halves combined by one shfl. Rest identical to R8.
// ---------------------------------------------------------------------------

#define FB_SHIFT 9              // 512 nodes per bucket; r<2^17 packs with c_local
#define SLAB_SHIFT 14           // 16384 edge slots per bucket slab (~1.9x max)

__device__ __forceinline__ unsigned bf16rn(float f) {
    unsigned x = __float_as_uint(f);
    unsigned r = ((x >> 16) & 1u) + 0x7fffu;   // RNE
    return (x + r) >> 16;
}
__device__ __forceinline__ float bf_lo(unsigned u) { return __uint_as_float(u << 16); }
__device__ __forceinline__ float bf_hi(unsigned u) { return __uint_as_float(u & 0xffff0000u); }

typedef __bf16 bf16x8 __attribute__((ext_vector_type(8)));
typedef float  f32x4  __attribute__((ext_vector_type(4)));

// ---- multisplit: bin edges by target bucket into fixed slabs --------------
__global__ __launch_bounds__(512) void k_binfill(const int* __restrict__ row,
                                                 const int* __restrict__ col,
                                                 int* __restrict__ bcur,
                                                 unsigned* __restrict__ bins, int E,
                                                 int nEB,
                                                 const float* __restrict__ W1,
                                                 const float* __restrict__ W2,
                                                 unsigned* __restrict__ Wt,
                                                 unsigned* __restrict__ W2t) {
    const int tid = threadIdx.x;

    if (blockIdx.x >= nEB) {            // ---- W-conversion tail blocks ----
        int w = (blockIdx.x - nEB) * 512 + tid;   // 0..11263
        if (w < 8192) {
            int n = w >> 6, kk = (w & 63) * 2;
            unsigned lo = bf16rn(W1[(size_t)kk * 128 + n]);
            unsigned hi = bf16rn(W1[(size_t)(kk + 1) * 128 + n]);
            Wt[w] = lo | (hi << 16);
        } else if (w < 8192 + 3072) {
            int u = w - 8192;
            int n = u >> 6, kk = (u & 63) * 2;
            unsigned lo = 0, hi = 0;
            if (n < 40) {
                lo = bf16rn(W2[(size_t)kk * 40 + n]);
                hi = bf16rn(W2[(size_t)(kk + 1) * 40 + n]);
            }
            W2t[u] = lo | (hi << 16);
        }
        return;
    }

    __shared__ int hist[256];
    __shared__ int scn[256];
    __shared__ int gbase[256];
    __shared__ int rcnt[256];
    __shared__ unsigned stage[4096];
    __shared__ unsigned char bkts[4096];

    const int base = blockIdx.x * 4096;

    if (tid < 256) { hist[tid] = 0; rcnt[tid] = 0; }
    __syncthreads();

    unsigned mypk[8];
    int      myb[8];
#pragma unroll
    for (int k = 0; k < 8; ++k) {
        int e = base + k * 512 + tid;
        if (e < E) {
            int r = row[e], c = col[e];
            int b = c >> FB_SHIFT;
            mypk[k] = ((unsigned)r << FB_SHIFT) | (unsigned)(c & ((1 << FB_SHIFT) - 1));
            myb[k] = b;
            atomicAdd(&hist[b], 1);
        } else {
            myb[k] = -1;
        }
    }
    __syncthreads();

    int v = 0;
    if (tid < 256) { v = hist[tid]; scn[tid] = v; }
    __syncthreads();
#pragma unroll
    for (int off = 1; off < 256; off <<= 1) {
        int t = (tid >= off && tid < 256) ? scn[tid - off] : 0;
        __syncthreads();
        if (tid < 256) scn[tid] += t;
        __syncthreads();
    }
    if (tid < 256) {
        int excl = scn[tid] - v;
        scn[tid] = excl;
    }
    __syncthreads();

#pragma unroll
    for (int k = 0; k < 8; ++k) {
        int b = myb[k];
        if (b >= 0) {
            int slot = scn[b] + atomicAdd(&rcnt[b], 1);
            stage[slot] = mypk[k];
            bkts[slot] = (unsigned char)b;
        }
    }

    if (tid < 256 && hist[tid] > 0) gbase[tid] = atomicAdd(&bcur[tid], hist[tid]);
    __syncthreads();

    int total = scn[255] + hist[255];
    const int cap = 1 << SLAB_SHIFT;
    for (int s = tid; s < total; s += 512) {
        unsigned u = stage[s];
        int b = bkts[s];
        int off = gbase[b] + (s - scn[b]);
        if (off < cap)                              // clamp (pathological only)
            bins[((size_t)b << SLAB_SHIFT) + off] = u;
    }
}

// ---- per-bucket: degree count + local scan + scatter; emits rpse + dis ----
__global__ __launch_bounds__(1024) void k_fill2(const unsigned* __restrict__ bins,
                                                const int* __restrict__ bcur,
                                                int2* __restrict__ rpse,
                                                float* __restrict__ dis,
                                                int* __restrict__ pair, int N) {
    __shared__ int cnt[512];
    __shared__ int lcur[512];
    __shared__ int ssum[256];
    const int tid = threadIdx.x;
    const int b = blockIdx.x;
    const int n0 = b << FB_SHIFT;
    const int start = b << SLAB_SHIFT;
    int count = bcur[b];
    if (count > (1 << SLAB_SHIFT)) count = 1 << SLAB_SHIFT;
    const int end = start + count;

    if (tid < 512) cnt[tid] = 0;
    __syncthreads();

    for (int i = start + tid; i < end; i += 1024)
        atomicAdd(&cnt[bins[i] & ((1 << FB_SHIFT) - 1)], 1);
    __syncthreads();

    int c0 = 0, c1 = 0, vsum = 0;
    if (tid < 256) {
        c0 = cnt[2 * tid]; c1 = cnt[2 * tid + 1];
        vsum = c0 + c1;
        ssum[tid] = vsum;
    }
    __syncthreads();
#pragma unroll
    for (int off = 1; off < 256; off <<= 1) {
        int u = (tid >= off && tid < 256) ? ssum[tid - off] : 0;
        __syncthreads();
        if (tid < 256) ssum[tid] += u;
        __syncthreads();
    }
    if (tid < 256) {
        int e0 = start + ssum[tid] - vsum;
        int e1 = e0 + c0;
        lcur[2 * tid] = e0;
        lcur[2 * tid + 1] = e1;
        int node0 = n0 + 2 * tid;
        int node1 = node0 + 1;
        if (node0 < N) {
            rpse[node0] = make_int2(e0, e1);
            dis[node0] = rsqrtf((float)(c0 + 1));   // +1 self-loop
        }
        if (node1 < N) {
            rpse[node1] = make_int2(e1, e1 + c1);
            dis[node1] = rsqrtf((float)(c1 + 1));
        }
    }
    __syncthreads();

    for (int i = start + tid; i < end; i += 1024) {
        unsigned u = bins[i];
        int pos = atomicAdd(&lcur[u & ((1 << FB_SHIFT) - 1)], 1);
        pair[pos] = (int)(u >> FB_SHIFT);
    }
}

// ---- x -> xbs2 (slice-major [2][N][32 uints]) = bf16x2(x * dis) -----------
__global__ __launch_bounds__(256) void k_cvtx(const float* __restrict__ x,
                                              const float* __restrict__ dis,
                                              unsigned* __restrict__ xbs2, int N) {
    int i = blockIdx.x * 256 + threadIdx.x;
    if (i >= N * 32) return;
    int n = i >> 5;                 // node
    int k2 = (i & 31) * 2;          // uint index within row (even, 0..62)
    float4 v = ((const float4*)x)[i];
    float d = dis[n];
    uint2 o;
    o.x = bf16rn(v.x * d) | (bf16rn(v.y * d) << 16);
    o.y = bf16rn(v.z * d) | (bf16rn(v.w * d) << 16);
    int s = k2 >> 5, pos = k2 & 31;  // slice (0/1), uint-in-slice (pos,pos+1 same slice)
    *(uint2*)(xbs2 + ((size_t)s * N + n) * 32 + pos) = o;
}

// ---- gather layer 1, 2x128B slices, paired half-waves ---------------------
// slice = blockIdx&1 (round-robin block->XCD: slice pinned to XCD parity).
// Wave per node; each 32-lane half covers the full 128B slice row of its
// edge (granule = 128B, the R8-proven delivery class); sub 0 even edges,
// sub 1 odd -> 16 edges in flight. Halves combined with one shfl.
__global__ __launch_bounds__(256) void k_gather1h(const unsigned* __restrict__ xbs2,
                                                  const int2* __restrict__ rpse,
                                                  const int* __restrict__ pair,
                                                  const float* __restrict__ dis,
                                                  unsigned* __restrict__ xab, int N) {
    const int bid = blockIdx.x;
    const int s = bid & 1;
    const int gw = (bid >> 1) * 4 + (threadIdx.x >> 6);
    if (gw >= N) return;
    const int lane = threadIdx.x & 63;
    const int sub = lane >> 5;          // 0: even edges, 1: odd edges
    const int sl  = lane & 31;          // uint within 128B slice row

    const unsigned* base = xbs2 + (size_t)s * N * 32;

    float ax = 0.f, ay = 0.f;
    if (sub == 0) {                     // self term (rows pre-scaled by dis)
        unsigned u = base[(size_t)gw * 32 + sl];
        ax = bf_lo(u); ay = bf_hi(u);
    }

    int2 rp = rpse[gw];
    int j = rp.x;
    const int je = rp.y;

    for (; j + 15 < je; j += 16) {      // 16 edges, 8 per half-wave
        int r0 = pair[j + sub];
        int r1 = pair[j + 2 + sub];
        int r2 = pair[j + 4 + sub];
        int r3 = pair[j + 6 + sub];
        int r4 = pair[j + 8 + sub];
        int r5 = pair[j + 10 + sub];
        int r6 = pair[j + 12 + sub];
        int r7 = pair[j + 14 + sub];
        unsigned u0 = base[(size_t)r0 * 32 + sl];
        unsigned u1 = base[(size_t)r1 * 32 + sl];
        unsigned u2 = base[(size_t)r2 * 32 + sl];
        unsigned u3 = base[(size_t)r3 * 32 + sl];
        unsigned u4 = base[(size_t)r4 * 32 + sl];
        unsigned u5 = base[(size_t)r5 * 32 + sl];
        unsigned u6 = base[(size_t)r6 * 32 + sl];
        unsigned u7 = base[(size_t)r7 * 32 + sl];
        ax += bf_lo(u0); ay += bf_hi(u0);
        ax += bf_lo(u1); ay += bf_hi(u1);
        ax += bf_lo(u2); ay += bf_hi(u2);
        ax += bf_lo(u3); ay += bf_hi(u3);
        ax += bf_lo(u4); ay += bf_hi(u4);
        ax += bf_lo(u5); ay += bf_hi(u5);
        ax += bf_lo(u6); ay += bf_hi(u6);
        ax += bf_lo(u7); ay += bf_hi(u7);
    }
    for (; j + 7 < je; j += 8) {        // 8 edges, 4 per half-wave
        int r0 = pair[j + sub];
        int r1 = pair[j + 2 + sub];
        int r2 = pair[j + 4 + sub];
        int r3 = pair[j + 6 + sub];
        unsigned u0 = base[(size_t)r0 * 32 + sl];
        unsigned u1 = base[(size_t)r1 * 32 + sl];
        unsigned u2 = base[(size_t)r2 * 32 + sl];
        unsigned u3 = base[(size_t)r3 * 32 + sl];
        ax += bf_lo(u0); ay += bf_hi(u0);
        ax += bf_lo(u1); ay += bf_hi(u1);
        ax += bf_lo(u2); ay += bf_hi(u2);
        ax += bf_lo(u3); ay += bf_hi(u3);
    }
    for (; j + 3 < je; j += 4) {        // 4 edges, 2 per half-wave
        int r0 = pair[j + sub];
        int r1 = pair[j + 2 + sub];
        unsigned u0 = base[(size_t)r0 * 32 + sl];
        unsigned u1 = base[(size_t)r1 * 32 + sl];
        ax += bf_lo(u0); ay += bf_hi(u0);
        ax += bf_lo(u1); ay += bf_hi(u1);
    }
    for (; j + 1 < je; j += 2) {        // 2 edges, 1 per half-wave
        int r0 = pair[j + sub];
        unsigned u0 = base[(size_t)r0 * 32 + sl];
        ax += bf_lo(u0); ay += bf_hi(u0);
    }
    if (j < je && sub == 0) {           // last odd edge
        int r0 = pair[j];
        unsigned u0 = base[(size_t)r0 * 32 + sl];
        ax += bf_lo(u0); ay += bf_hi(u0);
    }

    // combine halves, scale, pack, store (sub 0 only: 32 lanes x 4 B)
    ax += __shfl(ax, lane ^ 32, 64);
    ay += __shfl(ay, lane ^ 32, 64);
    if (sub == 0) {
        float dv = dis[gw];
        xab[(size_t)gw * 64 + s * 32 + sl] =
            bf16rn(dv * ax) | (bf16rn(dv * ay) << 16);
    }
}

// ---- fused GEMM1+GEMM2 (MFMA bf16) ----------------------------------------
// h = relu(xab @ W1t^T + b1)  (h kept in LDS, never hits global)
// Zb[M, pitch 32] = bf16( (h @ W2t^T) * dis[row] )  (20 uints used, 12 pad)
__global__ __launch_bounds__(256) void k_gemm12(const unsigned* __restrict__ Ab,
                                                const unsigned* __restrict__ Wt,
                                                const unsigned* __restrict__ W2t,
                                                const float* __restrict__ bias,
                                                const float* __restrict__ dis,
                                                unsigned* __restrict__ Zb, int M) {
    __shared__ char smem[70144];            // 34816 + 34816 + 512 (ldis)
    char* Abase = smem;
    char* Bbase = smem + 34816;
    float* ldis = (float*)(smem + 69632);

    const int tid = threadIdx.x;
    const int r0 = blockIdx.x * 128;

#pragma unroll
    for (int s = 0; s < 8; ++s) {
        int l = tid + s * 256;
        int row = l >> 4, q = l & 15;
        uint4 va = *(const uint4*)(Ab + (size_t)(r0 + row) * 64 + q * 4);
        *(uint4*)(Abase + row * 272 + q * 16) = va;
        uint4 vb = *(const uint4*)(Wt + (size_t)row * 64 + q * 4);
        *(uint4*)(Bbase + row * 272 + q * 16) = vb;
    }
    if (tid < 128) {
        int rr = r0 + tid;
        ldis[tid] = (rr < M) ? dis[rr] : 0.f;
    }
    __syncthreads();

    const int wv = tid >> 6, lane = tid & 63;
    const int quad = lane >> 4, mcol = lane & 15;

    // ---------------- GEMM1: acc1 = xab @ W1t^T ----------------
    f32x4 acc1[2][8];
#pragma unroll
    for (int rt = 0; rt < 2; ++rt)
#pragma unroll
        for (int ct = 0; ct < 8; ++ct) acc1[rt][ct] = (f32x4){0.f, 0.f, 0.f, 0.f};

#pragma unroll
    for (int ks = 0; ks < 4; ++ks) {
        bf16x8 a[2], b[8];
#pragma unroll
        for (int rt = 0; rt < 2; ++rt) {
            int row = wv * 32 + rt * 16 + mcol;
            a[rt] = *(const bf16x8*)(Abase + row * 272 + ks * 64 + quad * 16);
        }
#pragma unroll
        for (int ct = 0; ct < 8; ++ct) {
            int n = ct * 16 + mcol;
            b[ct] = *(const bf16x8*)(Bbase + n * 272 + ks * 64 + quad * 16);
        }
#pragma unroll
        for (int rt = 0; rt < 2; ++rt)
#pragma unroll
            for (int ct = 0; ct < 8; ++ct)
                acc1[rt][ct] = __builtin_amdgcn_mfma_f32_16x16x32_bf16(
                    a[rt], b[ct], acc1[rt][ct], 0, 0, 0);
    }
    __syncthreads();     // all waves done reading As (xab) and Bs (W1)

    // h (relu + bias, bf16) -> Bs region; W2 tile -> As region
    unsigned short* Hs = (unsigned short*)Bbase;     // pitch 136 ushorts
#pragma unroll
    for (int rt = 0; rt < 2; ++rt)
#pragma unroll
        for (int ct = 0; ct < 8; ++ct) {
            float bb = bias[ct * 16 + mcol];
#pragma unroll
            for (int r = 0; r < 4; ++r) {
                float v = acc1[rt][ct][r] + bb;
                v = v > 0.f ? v : 0.f;
                int orow = wv * 32 + rt * 16 + quad * 4 + r;
                Hs[orow * 136 + ct * 16 + mcol] = (unsigned short)bf16rn(v);
            }
        }
#pragma unroll
    for (int s = 0; s < 3; ++s) {
        int l = tid + s * 256;
        int row = l >> 4, q = l & 15;
        uint4 vb = *(const uint4*)(W2t + (size_t)row * 64 + q * 4);
        *(uint4*)(Abase + row * 272 + q * 16) = vb;
    }
    __syncthreads();

    // ---------------- GEMM2: acc2 = h @ W2t^T ----------------
    f32x4 acc2[2][3];
#pragma unroll
    for (int rt = 0; rt < 2; ++rt)
#pragma unroll
        for (int ct = 0; ct < 3; ++ct) acc2[rt][ct] = (f32x4){0.f, 0.f, 0.f, 0.f};

#pragma unroll
    for (int ks = 0; ks < 4; ++ks) {
        bf16x8 a[2], b[3];
#pragma unroll
        for (int rt = 0; rt < 2; ++rt) {
            int row = wv * 32 + rt * 16 + mcol;
            a[rt] = *(const bf16x8*)(Bbase + row * 272 + ks * 64 + quad * 16);
        }
#pragma unroll
        for (int ct = 0; ct < 3; ++ct) {
            int n = ct * 16 + mcol;
            b[ct] = *(const bf16x8*)(Abase + n * 272 + ks * 64 + quad * 16);
        }
#pragma unroll
        for (int rt = 0; rt < 2; ++rt)
#pragma unroll
            for (int ct = 0; ct < 3; ++ct)
                acc2[rt][ct] = __builtin_amdgcn_mfma_f32_16x16x32_bf16(
                    a[rt], b[ct], acc2[rt][ct], 0, 0, 0);
    }
    __syncthreads();

    // epilogue: scale by dis[row], pack bf16 rows at 56-ushort pitch (112 B)
    unsigned short* Zs = (unsigned short*)(Abase + 16384);  // above W2 (13056 B)
#pragma unroll
    for (int rt = 0; rt < 2; ++rt)
#pragma unroll
        for (int ct = 0; ct < 3; ++ct) {
#pragma unroll
            for (int r = 0; r < 4; ++r) {
                int orow = wv * 32 + rt * 16 + quad * 4 + r;
                float v = acc2[rt][ct][r] * ldis[orow];
                Zs[orow * 56 + ct * 16 + mcol] = (unsigned short)bf16rn(v);
            }
        }
    __syncthreads();

    if (tid < 128) {
        int rr = r0 + tid;
        if (rr < M) {
            const uint4* s4 = (const uint4*)(Abase + 16384 + tid * 112);
            uint4* d4 = (uint4*)(Zb + ((size_t)rr << 5));   // pitch 32 uints
#pragma unroll
            for (int q = 0; q < 5; ++q) d4[q] = s4[q];
        }
    }
}

// ---- gather layer 2: out[c] = b2 + dis[c] * (sum_r zb[r] + zb[c]) ---------
// Half-wave per edge stream; 16 edges in flight (8 per half).
// zb pitch = 32 uints (128 B): one aligned cache line per random row.
__global__ __launch_bounds__(256) void k_gather2(const unsigned* __restrict__ zb,
                                                 const int2* __restrict__ rpse,
                                                 const int* __restrict__ pair,
                                                 const float* __restrict__ dis,
                                                 const float* __restrict__ b2,
                                                 float* __restrict__ out, int N) {
    int gw = (blockIdx.x * 256 + threadIdx.x) >> 6;
    int lane = threadIdx.x & 63;
    if (gw >= N) return;
    int sub = lane >> 5;
    int sl  = lane & 31;
    int f   = (sl < 20) ? sl : 19;

    float2 acc = make_float2(0.f, 0.f);
    float dv = dis[gw];
    if (sub == 0) {                       // self term (rows pre-scaled by dis)
        unsigned u = zb[((size_t)gw << 5) + f];
        acc.x = bf_lo(u); acc.y = bf_hi(u);
    }

    int2 rp = rpse[gw];
    int j = rp.x, je = rp.y;
    for (; j + 15 < je; j += 16) {
        int rA = pair[j + sub];
        int rB = pair[j + 2 + sub];
        int rC = pair[j + 4 + sub];
        int rD = pair[j + 6 + sub];
        int rE = pair[j + 8 + sub];
        int rF = pair[j + 10 + sub];
        int rG = pair[j + 12 + sub];
        int rH = pair[j + 14 + sub];
        unsigned uA = zb[((size_t)rA << 5) + f];
        unsigned uB = zb[((size_t)rB << 5) + f];
        unsigned uC = zb[((size_t)rC << 5) + f];
        unsigned uD = zb[((size_t)rD << 5) + f];
        unsigned uE = zb[((size_t)rE << 5) + f];
        unsigned uF = zb[((size_t)rF << 5) + f];
        unsigned uG = zb[((size_t)rG << 5) + f];
        unsigned uH = zb[((size_t)rH << 5) + f];
        acc.x += bf_lo(uA); acc.y += bf_hi(uA);
        acc.x += bf_lo(uB); acc.y += bf_hi(uB);
        acc.x += bf_lo(uC); acc.y += bf_hi(uC);
        acc.x += bf_lo(uD); acc.y += bf_hi(uD);
        acc.x += bf_lo(uE); acc.y += bf_hi(uE);
        acc.x += bf_lo(uF); acc.y += bf_hi(uF);
        acc.x += bf_lo(uG); acc.y += bf_hi(uG);
        acc.x += bf_lo(uH); acc.y += bf_hi(uH);
    }
    for (; j + 7 < je; j += 8) {
        int rA = pair[j + sub];
        int rB = pair[j + 2 + sub];
        int rC = pair[j + 4 + sub];
        int rD = pair[j + 6 + sub];
        unsigned uA = zb[((size_t)rA << 5) + f];
        unsigned uB = zb[((size_t)rB << 5) + f];
        unsigned uC = zb[((size_t)rC << 5) + f];
        unsigned uD = zb[((size_t)rD << 5) + f];
        acc.x += bf_lo(uA); acc.y += bf_hi(uA);
        acc.x += bf_lo(uB); acc.y += bf_hi(uB);
        acc.x += bf_lo(uC); acc.y += bf_hi(uC);
        acc.x += bf_lo(uD); acc.y += bf_hi(uD);
    }
    for (; j + 3 < je; j += 4) {
        int rA = pair[j + sub];
        int rB = pair[j + 2 + sub];
        unsigned uA = zb[((size_t)rA << 5) + f];
        unsigned uB = zb[((size_t)rB << 5) + f];
        acc.x += bf_lo(uA); acc.y += bf_hi(uA);
        acc.x += bf_lo(uB); acc.y += bf_hi(uB);
    }
    for (; j + 1 < je; j += 2) {
        unsigned u = zb[((size_t)pair[j + sub] << 5) + f];
        acc.x += bf_lo(u); acc.y += bf_hi(u);
    }
    if (j < je && sub == 0) {
        unsigned u = zb[((size_t)pair[j] << 5) + f];
        acc.x += bf_lo(u); acc.y += bf_hi(u);
    }

    float bx = __shfl(acc.x, sl + 32, 64);
    float by = __shfl(acc.y, sl + 32, 64);
    if (sub == 0 && sl < 20) {
        float2 bias = ((const float2*)b2)[sl];
        float2 res = make_float2((acc.x + bx) * dv + bias.x,
                                 (acc.y + by) * dv + bias.y);
        ((float2*)(out + (size_t)gw * 40))[sl] = res;
    }
}

// ---------------------------------------------------------------------------
extern "C" void kernel_launch(void* const* d_in, const int* in_sizes, int n_in,
                              void* d_out, int out_size, void* d_ws, size_t ws_size,
                              hipStream_t stream) {
    const float* x  = (const float*)d_in[0];
    const int*   ei = (const int*)d_in[1];
    const float* W1 = (const float*)d_in[2];
    const float* b1 = (const float*)d_in[3];
    const float* W2 = (const float*)d_in[4];
    const float* b2 = (const float*)d_in[5];
    float* out = (float*)d_out;

    const int N = in_sizes[0] / 128;
    const int E = in_sizes[1] / 2;
    const int* row = ei;        // sources
    const int* col = ei + E;    // targets

    const int Np = (N + 255) & ~255;
    const int nbuck = (N + (1 << FB_SHIFT) - 1) >> FB_SHIFT;   // <= 256
    const int nEB = (E + 4095) / 4096;

    // workspace layout (4-byte units), ~82 MB total
    int*      bcur   = (int*)d_ws;                       // 256
    int2*     rpse   = (int2*)(bcur + 256);              // Np int2 (2*Np ints)
    float*    dis    = (float*)(rpse + Np);              // Np
    unsigned* Wt     = (unsigned*)(dis + Np);            // 8192 (W1t bf16)
    unsigned* W2t    = Wt + 8192;                        // 3072 (W2t bf16, 48 rows)
    int*      pair   = (int*)(W2t + 3072);               // 256<<14 slabbed
    unsigned* xbs2   = (unsigned*)(pair + ((size_t)256 << SLAB_SHIFT)); // N*64 sliced
    unsigned* xab    = xbs2 + (size_t)N * 64;            // N*64 (bf16 A*x, row-major)
    unsigned* zb     = xab + (size_t)N * 64;             // N*32 (bf16 z*dis, padded)
    unsigned* bins   = (unsigned*)xab;  // alias: slabbed, dead before gather1

    // slab-bucketed CSC build (no global histogram/scan needed)
    hipMemsetAsync(bcur, 0, 256 * sizeof(int), stream);
    k_binfill<<<nEB + 22, 512, 0, stream>>>(row, col, bcur, bins, E, nEB,
                                            W1, W2, Wt, W2t);
    k_fill2<<<nbuck, 1024, 0, stream>>>(bins, bcur, rpse, dis, pair, N);

    // x conversion into 2-slice layout (full grid, reads dis)
    k_cvtx<<<(N * 32 + 255) / 256, 256, 0, stream>>>(x, dis, xbs2, N);

    // layer 1 gather, 2x128B-sliced: xab = bf16(A x)
    k_gather1h<<<((N + 3) / 4) * 2, 256, 0, stream>>>(xbs2, rpse, pair, dis, xab, N);

    // fused GEMMs: zb = bf16((relu(xab@W1+b1) @ W2) * dis)   [MFMA]
    k_gemm12<<<(N + 127) / 128, 256, 0, stream>>>(xab, Wt, W2t, b1, dis, zb, N);

    // layer 2 gather: out = b2 + dis*(sum zb)
    k_gather2<<<(N + 3) / 4, 256, 0, stream>>>(zb, rpse, pair, dis, b2, out, N);
}

// Round 12
// 261.132 us; speedup vs baseline: 1.6796x; 1.1210x over previous
//
#include <hip/hip_runtime.h>
#include <hip/hip_bf16.h>

// ---------------------------------------------------------------------------
// 2-layer GCN, atomic-free CSC gather, bf16 payloads + bf16 MFMA GEMMs.
// dis[] is folded into the gathered payloads (xb = x*dis, zb = z*dis), so
// edge records are source-index-only (4 B). Aggregation at target c:
//   A·v|_c = dis[c] * (sum_r payload[r] + payload[c])
// Layer 1: h = relu((A x) @ W1 + b1)   [reassociated]
// Layer 2: out = A (h @ W2) + b2
//
// R8: SLAB buckets — k_bcount/k_bscanw deleted; fill2 emits int2 rpse.
// R9-R11: slicing design space fully measured and CLOSED:
//   256B granule / 25.6MB table (no L2 fit): 190MB fetch, 63us  <- best
//   128B granule / 12.8MB table (no L2 fit): 168MB fetch, 95us
//    32B granule /  3.2MB table (L2 fit):     65MB fetch, 167-249us
// L2 residency needs <=4MB slice => <=32B granule => delivery collapse.
// gather1's row-major form is the structural floor (~3 TB/s L2-miss path).
// R12: revert to exact R8 (best measured: 262.0us).
// ---------------------------------------------------------------------------

#define FB_SHIFT 9              // 512 nodes per bucket; r<2^17 packs with c_local
#define SLAB_SHIFT 14           // 16384 edge slots per bucket slab (~1.9x max)

__device__ __forceinline__ unsigned bf16rn(float f) {
    unsigned x = __float_as_uint(f);
    unsigned r = ((x >> 16) & 1u) + 0x7fffu;   // RNE
    return (x + r) >> 16;
}
__device__ __forceinline__ float bf_lo(unsigned u) { return __uint_as_float(u << 16); }
__device__ __forceinline__ float bf_hi(unsigned u) { return __uint_as_float(u & 0xffff0000u); }

typedef __bf16 bf16x8 __attribute__((ext_vector_type(8)));
typedef float  f32x4  __attribute__((ext_vector_type(4)));

// ---- multisplit: bin edges by target bucket into fixed slabs --------------
__global__ __launch_bounds__(512) void k_binfill(const int* __restrict__ row,
                                                 const int* __restrict__ col,
                                                 int* __restrict__ bcur,
                                                 unsigned* __restrict__ bins, int E,
                                                 int nEB,
                                                 const float* __restrict__ W1,
                                                 const float* __restrict__ W2,
                                                 unsigned* __restrict__ Wt,
                                                 unsigned* __restrict__ W2t) {
    const int tid = threadIdx.x;

    if (blockIdx.x >= nEB) {            // ---- W-conversion tail blocks ----
        int w = (blockIdx.x - nEB) * 512 + tid;   // 0..11263
        if (w < 8192) {
            int n = w >> 6, kk = (w & 63) * 2;
            unsigned lo = bf16rn(W1[(size_t)kk * 128 + n]);
            unsigned hi = bf16rn(W1[(size_t)(kk + 1) * 128 + n]);
            Wt[w] = lo | (hi << 16);
        } else if (w < 8192 + 3072) {
            int u = w - 8192;
            int n = u >> 6, kk = (u & 63) * 2;
            unsigned lo = 0, hi = 0;
            if (n < 40) {
                lo = bf16rn(W2[(size_t)kk * 40 + n]);
                hi = bf16rn(W2[(size_t)(kk + 1) * 40 + n]);
            }
            W2t[u] = lo | (hi << 16);
        }
        return;
    }

    __shared__ int hist[256];
    __shared__ int scn[256];
    __shared__ int gbase[256];
    __shared__ int rcnt[256];
    __shared__ unsigned stage[4096];
    __shared__ unsigned char bkts[4096];

    const int base = blockIdx.x * 4096;

    if (tid < 256) { hist[tid] = 0; rcnt[tid] = 0; }
    __syncthreads();

    unsigned mypk[8];
    int      myb[8];
#pragma unroll
    for (int k = 0; k < 8; ++k) {
        int e = base + k * 512 + tid;
        if (e < E) {
            int r = row[e], c = col[e];
            int b = c >> FB_SHIFT;
            mypk[k] = ((unsigned)r << FB_SHIFT) | (unsigned)(c & ((1 << FB_SHIFT) - 1));
            myb[k] = b;
            atomicAdd(&hist[b], 1);
        } else {
            myb[k] = -1;
        }
    }
    __syncthreads();

    int v = 0;
    if (tid < 256) { v = hist[tid]; scn[tid] = v; }
    __syncthreads();
#pragma unroll
    for (int off = 1; off < 256; off <<= 1) {
        int t = (tid >= off && tid < 256) ? scn[tid - off] : 0;
        __syncthreads();
        if (tid < 256) scn[tid] += t;
        __syncthreads();
    }
    if (tid < 256) {
        int excl = scn[tid] - v;
        scn[tid] = excl;
    }
    __syncthreads();

#pragma unroll
    for (int k = 0; k < 8; ++k) {
        int b = myb[k];
        if (b >= 0) {
            int slot = scn[b] + atomicAdd(&rcnt[b], 1);
            stage[slot] = mypk[k];
            bkts[slot] = (unsigned char)b;
        }
    }

    if (tid < 256 && hist[tid] > 0) gbase[tid] = atomicAdd(&bcur[tid], hist[tid]);
    __syncthreads();

    int total = scn[255] + hist[255];
    const int cap = 1 << SLAB_SHIFT;
    for (int s = tid; s < total; s += 512) {
        unsigned u = stage[s];
        int b = bkts[s];
        int off = gbase[b] + (s - scn[b]);
        if (off < cap)                              // clamp (pathological only)
            bins[((size_t)b << SLAB_SHIFT) + off] = u;
    }
}

// ---- per-bucket: degree count + local scan + scatter; emits rpse + dis ----
__global__ __launch_bounds__(1024) void k_fill2(const unsigned* __restrict__ bins,
                                                const int* __restrict__ bcur,
                                                int2* __restrict__ rpse,
                                                float* __restrict__ dis,
                                                int* __restrict__ pair, int N) {
    __shared__ int cnt[512];
    __shared__ int lcur[512];
    __shared__ int ssum[256];
    const int tid = threadIdx.x;
    const int b = blockIdx.x;
    const int n0 = b << FB_SHIFT;
    const int start = b << SLAB_SHIFT;
    int count = bcur[b];
    if (count > (1 << SLAB_SHIFT)) count = 1 << SLAB_SHIFT;
    const int end = start + count;

    if (tid < 512) cnt[tid] = 0;
    __syncthreads();

    for (int i = start + tid; i < end; i += 1024)
        atomicAdd(&cnt[bins[i] & ((1 << FB_SHIFT) - 1)], 1);
    __syncthreads();

    int c0 = 0, c1 = 0, vsum = 0;
    if (tid < 256) {
        c0 = cnt[2 * tid]; c1 = cnt[2 * tid + 1];
        vsum = c0 + c1;
        ssum[tid] = vsum;
    }
    __syncthreads();
#pragma unroll
    for (int off = 1; off < 256; off <<= 1) {
        int u = (tid >= off && tid < 256) ? ssum[tid - off] : 0;
        __syncthreads();
        if (tid < 256) ssum[tid] += u;
        __syncthreads();
    }
    if (tid < 256) {
        int e0 = start + ssum[tid] - vsum;
        int e1 = e0 + c0;
        lcur[2 * tid] = e0;
        lcur[2 * tid + 1] = e1;
        int node0 = n0 + 2 * tid;
        int node1 = node0 + 1;
        if (node0 < N) {
            rpse[node0] = make_int2(e0, e1);
            dis[node0] = rsqrtf((float)(c0 + 1));   // +1 self-loop
        }
        if (node1 < N) {
            rpse[node1] = make_int2(e1, e1 + c1);
            dis[node1] = rsqrtf((float)(c1 + 1));
        }
    }
    __syncthreads();

    for (int i = start + tid; i < end; i += 1024) {
        unsigned u = bins[i];
        int pos = atomicAdd(&lcur[u & ((1 << FB_SHIFT) - 1)], 1);
        pair[pos] = (int)(u >> FB_SHIFT);
    }
}

// ---- x -> xb = bf16x2(x * dis), full-grid streaming, float4/lane ----------
__global__ __launch_bounds__(256) void k_cvtx(const float* __restrict__ x,
                                              const float* __restrict__ dis,
                                              unsigned* __restrict__ xb, int n32) {
    int i = blockIdx.x * 256 + threadIdx.x;
    if (i >= n32) return;
    float4 v = ((const float4*)x)[i];
    float d = dis[i >> 5];
    uint2 o;
    o.x = bf16rn(v.x * d) | (bf16rn(v.y * d) << 16);
    o.y = bf16rn(v.z * d) | (bf16rn(v.w * d) << 16);
    ((uint2*)xb)[i] = o;
}

// ---- gather layer 1: xab[c] = bf16(dis[c] * (sum_r xb[r] + xb[c])) --------
// Wave per node; index-only pair records; 8 gathers in flight. At the
// structural floor: 190MB L2-miss traffic at ~3 TB/s (R9-R11 alternatives
// all slower — granule-vs-L2-residency tradeoff has no better point).
__global__ __launch_bounds__(256) void k_gather1(const unsigned* __restrict__ xb,
                                                 const int2* __restrict__ rpse,
                                                 const int* __restrict__ pair,
                                                 const float* __restrict__ dis,
                                                 unsigned* __restrict__ xab, int N) {
    int gw = (blockIdx.x * 256 + threadIdx.x) >> 6;
    int lane = threadIdx.x & 63;
    if (gw >= N) return;
    float dv = dis[gw];
    unsigned us = xb[(size_t)gw * 64 + lane];
    float2 acc = make_float2(bf_lo(us), bf_hi(us));   // self term (rows pre-scaled)
    int2 rp = rpse[gw];
    int j = rp.x, je = rp.y;

    for (; j + 7 < je; j += 8) {
        int r0 = pair[j],     r1 = pair[j + 1], r2 = pair[j + 2], r3 = pair[j + 3];
        int r4 = pair[j + 4], r5 = pair[j + 5], r6 = pair[j + 6], r7 = pair[j + 7];
        unsigned a0 = xb[(size_t)r0 * 64 + lane];
        unsigned a1 = xb[(size_t)r1 * 64 + lane];
        unsigned a2 = xb[(size_t)r2 * 64 + lane];
        unsigned a3 = xb[(size_t)r3 * 64 + lane];
        unsigned a4 = xb[(size_t)r4 * 64 + lane];
        unsigned a5 = xb[(size_t)r5 * 64 + lane];
        unsigned a6 = xb[(size_t)r6 * 64 + lane];
        unsigned a7 = xb[(size_t)r7 * 64 + lane];
        acc.x += bf_lo(a0); acc.y += bf_hi(a0);
        acc.x += bf_lo(a1); acc.y += bf_hi(a1);
        acc.x += bf_lo(a2); acc.y += bf_hi(a2);
        acc.x += bf_lo(a3); acc.y += bf_hi(a3);
        acc.x += bf_lo(a4); acc.y += bf_hi(a4);
        acc.x += bf_lo(a5); acc.y += bf_hi(a5);
        acc.x += bf_lo(a6); acc.y += bf_hi(a6);
        acc.x += bf_lo(a7); acc.y += bf_hi(a7);
    }
    for (; j + 3 < je; j += 4) {
        int r0 = pair[j], r1 = pair[j + 1], r2 = pair[j + 2], r3 = pair[j + 3];
        unsigned a0 = xb[(size_t)r0 * 64 + lane];
        unsigned a1 = xb[(size_t)r1 * 64 + lane];
        unsigned a2 = xb[(size_t)r2 * 64 + lane];
        unsigned a3 = xb[(size_t)r3 * 64 + lane];
        acc.x += bf_lo(a0); acc.y += bf_hi(a0);
        acc.x += bf_lo(a1); acc.y += bf_hi(a1);
        acc.x += bf_lo(a2); acc.y += bf_hi(a2);
        acc.x += bf_lo(a3); acc.y += bf_hi(a3);
    }
    for (; j < je; ++j) {
        unsigned a0 = xb[(size_t)pair[j] * 64 + lane];
        acc.x += bf_lo(a0); acc.y += bf_hi(a0);
    }
    xab[(size_t)gw * 64 + lane] = bf16rn(dv * acc.x) | (bf16rn(dv * acc.y) << 16);
}

// ---- fused GEMM1+GEMM2 (MFMA bf16) ----------------------------------------
// h = relu(xab @ W1t^T + b1)  (h kept in LDS, never hits global)
// Zb[M, pitch 32] = bf16( (h @ W2t^T) * dis[row] )  (20 uints used, 12 pad)
__global__ __launch_bounds__(256) void k_gemm12(const unsigned* __restrict__ Ab,
                                                const unsigned* __restrict__ Wt,
                                                const unsigned* __restrict__ W2t,
                                                const float* __restrict__ bias,
                                                const float* __restrict__ dis,
                                                unsigned* __restrict__ Zb, int M) {
    __shared__ char smem[70144];            // 34816 + 34816 + 512 (ldis)
    char* Abase = smem;
    char* Bbase = smem + 34816;
    float* ldis = (float*)(smem + 69632);

    const int tid = threadIdx.x;
    const int r0 = blockIdx.x * 128;

#pragma unroll
    for (int s = 0; s < 8; ++s) {
        int l = tid + s * 256;
        int row = l >> 4, q = l & 15;
        uint4 va = *(const uint4*)(Ab + (size_t)(r0 + row) * 64 + q * 4);
        *(uint4*)(Abase + row * 272 + q * 16) = va;
        uint4 vb = *(const uint4*)(Wt + (size_t)row * 64 + q * 4);
        *(uint4*)(Bbase + row * 272 + q * 16) = vb;
    }
    if (tid < 128) {
        int rr = r0 + tid;
        ldis[tid] = (rr < M) ? dis[rr] : 0.f;
    }
    __syncthreads();

    const int wv = tid >> 6, lane = tid & 63;
    const int quad = lane >> 4, mcol = lane & 15;

    // ---------------- GEMM1: acc1 = xab @ W1t^T ----------------
    f32x4 acc1[2][8];
#pragma unroll
    for (int rt = 0; rt < 2; ++rt)
#pragma unroll
        for (int ct = 0; ct < 8; ++ct) acc1[rt][ct] = (f32x4){0.f, 0.f, 0.f, 0.f};

#pragma unroll
    for (int ks = 0; ks < 4; ++ks) {
        bf16x8 a[2], b[8];
#pragma unroll
        for (int rt = 0; rt < 2; ++rt) {
            int row = wv * 32 + rt * 16 + mcol;
            a[rt] = *(const bf16x8*)(Abase + row * 272 + ks * 64 + quad * 16);
        }
#pragma unroll
        for (int ct = 0; ct < 8; ++ct) {
            int n = ct * 16 + mcol;
            b[ct] = *(const bf16x8*)(Bbase + n * 272 + ks * 64 + quad * 16);
        }
#pragma unroll
        for (int rt = 0; rt < 2; ++rt)
#pragma unroll
            for (int ct = 0; ct < 8; ++ct)
                acc1[rt][ct] = __builtin_amdgcn_mfma_f32_16x16x32_bf16(
                    a[rt], b[ct], acc1[rt][ct], 0, 0, 0);
    }
    __syncthreads();     // all waves done reading As (xab) and Bs (W1)

    // h (relu + bias, bf16) -> Bs region; W2 tile -> As region
    unsigned short* Hs = (unsigned short*)Bbase;     // pitch 136 ushorts
#pragma unroll
    for (int rt = 0; rt < 2; ++rt)
#pragma unroll
        for (int ct = 0; ct < 8; ++ct) {
            float bb = bias[ct * 16 + mcol];
#pragma unroll
            for (int r = 0; r < 4; ++r) {
                float v = acc1[rt][ct][r] + bb;
                v = v > 0.f ? v : 0.f;
                int orow = wv * 32 + rt * 16 + quad * 4 + r;
                Hs[orow * 136 + ct * 16 + mcol] = (unsigned short)bf16rn(v);
            }
        }
#pragma unroll
    for (int s = 0; s < 3; ++s) {
        int l = tid + s * 256;
        int row = l >> 4, q = l & 15;
        uint4 vb = *(const uint4*)(W2t + (size_t)row * 64 + q * 4);
        *(uint4*)(Abase + row * 272 + q * 16) = vb;
    }
    __syncthreads();

    // ---------------- GEMM2: acc2 = h @ W2t^T ----------------
    f32x4 acc2[2][3];
#pragma unroll
    for (int rt = 0; rt < 2; ++rt)
#pragma unroll
        for (int ct = 0; ct < 3; ++ct) acc2[rt][ct] = (f32x4){0.f, 0.f, 0.f, 0.f};

#pragma unroll
    for (int ks = 0; ks < 4; ++ks) {
        bf16x8 a[2], b[3];
#pragma unroll
        for (int rt = 0; rt < 2; ++rt) {
            int row = wv * 32 + rt * 16 + mcol;
            a[rt] = *(const bf16x8*)(Bbase + row * 272 + ks * 64 + quad * 16);
        }
#pragma unroll
        for (int ct = 0; ct < 3; ++ct) {
            int n = ct * 16 + mcol;
            b[ct] = *(const bf16x8*)(Abase + n * 272 + ks * 64 + quad * 16);
        }
#pragma unroll
        for (int rt = 0; rt < 2; ++rt)
#pragma unroll
            for (int ct = 0; ct < 3; ++ct)
                acc2[rt][ct] = __builtin_amdgcn_mfma_f32_16x16x32_bf16(
                    a[rt], b[ct], acc2[rt][ct], 0, 0, 0);
    }
    __syncthreads();

    // epilogue: scale by dis[row], pack bf16 rows at 56-ushort pitch (112 B)
    unsigned short* Zs = (unsigned short*)(Abase + 16384);  // above W2 (13056 B)
#pragma unroll
    for (int rt = 0; rt < 2; ++rt)
#pragma unroll
        for (int ct = 0; ct < 3; ++ct) {
#pragma unroll
            for (int r = 0; r < 4; ++r) {
                int orow = wv * 32 + rt * 16 + quad * 4 + r;
                float v = acc2[rt][ct][r] * ldis[orow];
                Zs[orow * 56 + ct * 16 + mcol] = (unsigned short)bf16rn(v);
            }
        }
    __syncthreads();

    if (tid < 128) {
        int rr = r0 + tid;
        if (rr < M) {
            const uint4* s4 = (const uint4*)(Abase + 16384 + tid * 112);
            uint4* d4 = (uint4*)(Zb + ((size_t)rr << 5));   // pitch 32 uints
#pragma unroll
            for (int q = 0; q < 5; ++q) d4[q] = s4[q];
        }
    }
}

// ---- gather layer 2: out[c] = b2 + dis[c] * (sum_r zb[r] + zb[c]) ---------
// Half-wave per edge stream; 16 edges in flight (8 per half).
// zb pitch = 32 uints (128 B): one aligned cache line per random row.
__global__ __launch_bounds__(256) void k_gather2(const unsigned* __restrict__ zb,
                                                 const int2* __restrict__ rpse,
                                                 const int* __restrict__ pair,
                                                 const float* __restrict__ dis,
                                                 const float* __restrict__ b2,
                                                 float* __restrict__ out, int N) {
    int gw = (blockIdx.x * 256 + threadIdx.x) >> 6;
    int lane = threadIdx.x & 63;
    if (gw >= N) return;
    int sub = lane >> 5;
    int sl  = lane & 31;
    int f   = (sl < 20) ? sl : 19;

    float2 acc = make_float2(0.f, 0.f);
    float dv = dis[gw];
    if (sub == 0) {                       // self term (rows pre-scaled by dis)
        unsigned u = zb[((size_t)gw << 5) + f];
        acc.x = bf_lo(u); acc.y = bf_hi(u);
    }

    int2 rp = rpse[gw];
    int j = rp.x, je = rp.y;
    for (; j + 15 < je; j += 16) {
        int rA = pair[j + sub];
        int rB = pair[j + 2 + sub];
        int rC = pair[j + 4 + sub];
        int rD = pair[j + 6 + sub];
        int rE = pair[j + 8 + sub];
        int rF = pair[j + 10 + sub];
        int rG = pair[j + 12 + sub];
        int rH = pair[j + 14 + sub];
        unsigned uA = zb[((size_t)rA << 5) + f];
        unsigned uB = zb[((size_t)rB << 5) + f];
        unsigned uC = zb[((size_t)rC << 5) + f];
        unsigned uD = zb[((size_t)rD << 5) + f];
        unsigned uE = zb[((size_t)rE << 5) + f];
        unsigned uF = zb[((size_t)rF << 5) + f];
        unsigned uG = zb[((size_t)rG << 5) + f];
        unsigned uH = zb[((size_t)rH << 5) + f];
        acc.x += bf_lo(uA); acc.y += bf_hi(uA);
        acc.x += bf_lo(uB); acc.y += bf_hi(uB);
        acc.x += bf_lo(uC); acc.y += bf_hi(uC);
        acc.x += bf_lo(uD); acc.y += bf_hi(uD);
        acc.x += bf_lo(uE); acc.y += bf_hi(uE);
        acc.x += bf_lo(uF); acc.y += bf_hi(uF);
        acc.x += bf_lo(uG); acc.y += bf_hi(uG);
        acc.x += bf_lo(uH); acc.y += bf_hi(uH);
    }
    for (; j + 7 < je; j += 8) {
        int rA = pair[j + sub];
        int rB = pair[j + 2 + sub];
        int rC = pair[j + 4 + sub];
        int rD = pair[j + 6 + sub];
        unsigned uA = zb[((size_t)rA << 5) + f];
        unsigned uB = zb[((size_t)rB << 5) + f];
        unsigned uC = zb[((size_t)rC << 5) + f];
        unsigned uD = zb[((size_t)rD << 5) + f];
        acc.x += bf_lo(uA); acc.y += bf_hi(uA);
        acc.x += bf_lo(uB); acc.y += bf_hi(uB);
        acc.x += bf_lo(uC); acc.y += bf_hi(uC);
        acc.x += bf_lo(uD); acc.y += bf_hi(uD);
    }
    for (; j + 3 < je; j += 4) {
        int rA = pair[j + sub];
        int rB = pair[j + 2 + sub];
        unsigned uA = zb[((size_t)rA << 5) + f];
        unsigned uB = zb[((size_t)rB << 5) + f];
        acc.x += bf_lo(uA); acc.y += bf_hi(uA);
        acc.x += bf_lo(uB); acc.y += bf_hi(uB);
    }
    for (; j + 1 < je; j += 2) {
        unsigned u = zb[((size_t)pair[j + sub] << 5) + f];
        acc.x += bf_lo(u); acc.y += bf_hi(u);
    }
    if (j < je && sub == 0) {
        unsigned u = zb[((size_t)pair[j] << 5) + f];
        acc.x += bf_lo(u); acc.y += bf_hi(u);
    }

    float bx = __shfl(acc.x, sl + 32, 64);
    float by = __shfl(acc.y, sl + 32, 64);
    if (sub == 0 && sl < 20) {
        float2 bias = ((const float2*)b2)[sl];
        float2 res = make_float2((acc.x + bx) * dv + bias.x,
                                 (acc.y + by) * dv + bias.y);
        ((float2*)(out + (size_t)gw * 40))[sl] = res;
    }
}

// ---------------------------------------------------------------------------
extern "C" void kernel_launch(void* const* d_in, const int* in_sizes, int n_in,
                              void* d_out, int out_size, void* d_ws, size_t ws_size,
                              hipStream_t stream) {
    const float* x  = (const float*)d_in[0];
    const int*   ei = (const int*)d_in[1];
    const float* W1 = (const float*)d_in[2];
    const float* b1 = (const float*)d_in[3];
    const float* W2 = (const float*)d_in[4];
    const float* b2 = (const float*)d_in[5];
    float* out = (float*)d_out;

    const int N = in_sizes[0] / 128;
    const int E = in_sizes[1] / 2;
    const int* row = ei;        // sources
    const int* col = ei + E;    // targets

    const int Np = (N + 255) & ~255;
    const int nbuck = (N + (1 << FB_SHIFT) - 1) >> FB_SHIFT;   // <= 256
    const int nEB = (E + 4095) / 4096;

    // workspace layout (4-byte units), ~82 MB total
    int*      bcur   = (int*)d_ws;                       // 256
    int2*     rpse   = (int2*)(bcur + 256);              // Np int2 (2*Np ints)
    float*    dis    = (float*)(rpse + Np);              // Np
    unsigned* Wt     = (unsigned*)(dis + Np);            // 8192 (W1t bf16)
    unsigned* W2t    = Wt + 8192;                        // 3072 (W2t bf16, 48 rows)
    int*      pair   = (int*)(W2t + 3072);               // 256<<14 slabbed
    unsigned* xb     = (unsigned*)(pair + ((size_t)256 << SLAB_SHIFT)); // N*64
    unsigned* xab    = xb + (size_t)N * 64;              // N*64 (bf16 A*x)
    unsigned* zb     = xab + (size_t)N * 64;             // N*32 (bf16 z*dis, padded)
    unsigned* bins   = (unsigned*)xab;  // alias: slabbed, dead before gather1

    // slab-bucketed CSC build (no global histogram/scan needed)
    hipMemsetAsync(bcur, 0, 256 * sizeof(int), stream);
    k_binfill<<<nEB + 22, 512, 0, stream>>>(row, col, bcur, bins, E, nEB,
                                            W1, W2, Wt, W2t);
    k_fill2<<<nbuck, 1024, 0, stream>>>(bins, bcur, rpse, dis, pair, N);

    // x conversion (full grid, reads dis)
    k_cvtx<<<(N * 32 + 255) / 256, 256, 0, stream>>>(x, dis, xb, N * 32);

    // layer 1 gather: xab = bf16(A x)
    k_gather1<<<(N + 3) / 4, 256, 0, stream>>>(xb, rpse, pair, dis, xab, N);

    // fused GEMMs: zb = bf16((relu(xab@W1+b1) @ W2) * dis)   [MFMA]
    k_gemm12<<<(N + 127) / 128, 256, 0, stream>>>(xab, Wt, W2t, b1, dis, zb, N);

    // layer 2 gather: out = b2 + dis*(sum zb)
    k_gather2<<<(N + 3) / 4, 256, 0, stream>>>(zb, rpse, pair, dis, b2, out, N);
}

// Round 13
// 254.995 us; speedup vs baseline: 1.7200x; 1.0241x over previous
//
#include <hip/hip_runtime.h>
#include <hip/hip_bf16.h>

// ---------------------------------------------------------------------------
// 2-layer GCN, atomic-free CSC gather, bf16 payloads + bf16 MFMA GEMMs.
// Edge records are source-index-only (4 B). Aggregation at target c:
//   A·v|_c = dis[c] * (sum_r dis[r]*x[r] + dis[c]*x[c])
// Layer 1: h = relu((A x) @ W1 + b1)   [reassociated]
// Layer 2: out = A (h @ W2) + b2
//
// R8: SLAB buckets — k_bcount/k_bscanw deleted; fill2 emits int2 rpse.
// R9-R11: gather1 slicing space measured and CLOSED (256B row-major is the
// floor: ~3 TB/s L2-miss fill; smaller granules collapse delivery).
// R13: xb stores RAW bf16(x) (no dis pre-scale) -> conversion has no
// build-chain dependency and rides k_binfill's tail blocks (overlaps the
// atomic-latency edge blocks); standalone k_cvtx DELETED. gather1 applies
// dis[r] per edge via scalar loads from the 400KB L2-resident dis table,
// accumulating with fma (same VALU count as the old add).
// ---------------------------------------------------------------------------

#define FB_SHIFT 9              // 512 nodes per bucket; r<2^17 packs with c_local
#define SLAB_SHIFT 14           // 16384 edge slots per bucket slab (~1.9x max)

__device__ __forceinline__ unsigned bf16rn(float f) {
    unsigned x = __float_as_uint(f);
    unsigned r = ((x >> 16) & 1u) + 0x7fffu;   // RNE
    return (x + r) >> 16;
}
__device__ __forceinline__ float bf_lo(unsigned u) { return __uint_as_float(u << 16); }
__device__ __forceinline__ float bf_hi(unsigned u) { return __uint_as_float(u & 0xffff0000u); }

typedef __bf16 bf16x8 __attribute__((ext_vector_type(8)));
typedef float  f32x4  __attribute__((ext_vector_type(4)));

// ---- multisplit: bin edges into fixed slabs; tails: W cvt + raw x cvt -----
__global__ __launch_bounds__(512) void k_binfill(const int* __restrict__ row,
                                                 const int* __restrict__ col,
                                                 int* __restrict__ bcur,
                                                 unsigned* __restrict__ bins, int E,
                                                 int nEB,
                                                 const float* __restrict__ W1,
                                                 const float* __restrict__ W2,
                                                 unsigned* __restrict__ Wt,
                                                 unsigned* __restrict__ W2t,
                                                 const float* __restrict__ x,
                                                 unsigned* __restrict__ xb, int n32) {
    const int tid = threadIdx.x;

    if (blockIdx.x >= nEB) {            // ---- conversion tail blocks ----
        int t = blockIdx.x - nEB;
        if (t < 22) {                   // W1/W2 -> transposed bf16 (11264 items)
            int w = t * 512 + tid;
            if (w < 8192) {
                int n = w >> 6, kk = (w & 63) * 2;
                unsigned lo = bf16rn(W1[(size_t)kk * 128 + n]);
                unsigned hi = bf16rn(W1[(size_t)(kk + 1) * 128 + n]);
                Wt[w] = lo | (hi << 16);
            } else if (w < 8192 + 3072) {
                int u = w - 8192;
                int n = u >> 6, kk = (u & 63) * 2;
                unsigned lo = 0, hi = 0;
                if (n < 40) {
                    lo = bf16rn(W2[(size_t)kk * 40 + n]);
                    hi = bf16rn(W2[(size_t)(kk + 1) * 40 + n]);
                }
                W2t[u] = lo | (hi << 16);
            }
        } else {                        // x -> raw bf16 xb (no dis dependency)
            int i = (t - 22) * 512 + tid;
            if (i < n32) {
                float4 v = ((const float4*)x)[i];
                uint2 o;
                o.x = bf16rn(v.x) | (bf16rn(v.y) << 16);
                o.y = bf16rn(v.z) | (bf16rn(v.w) << 16);
                ((uint2*)xb)[i] = o;
            }
        }
        return;
    }

    __shared__ int hist[256];
    __shared__ int scn[256];
    __shared__ int gbase[256];
    __shared__ int rcnt[256];
    __shared__ unsigned stage[4096];
    __shared__ unsigned char bkts[4096];

    const int base = blockIdx.x * 4096;

    if (tid < 256) { hist[tid] = 0; rcnt[tid] = 0; }
    __syncthreads();

    unsigned mypk[8];
    int      myb[8];
#pragma unroll
    for (int k = 0; k < 8; ++k) {
        int e = base + k * 512 + tid;
        if (e < E) {
            int r = row[e], c = col[e];
            int b = c >> FB_SHIFT;
            mypk[k] = ((unsigned)r << FB_SHIFT) | (unsigned)(c & ((1 << FB_SHIFT) - 1));
            myb[k] = b;
            atomicAdd(&hist[b], 1);
        } else {
            myb[k] = -1;
        }
    }
    __syncthreads();

    int v = 0;
    if (tid < 256) { v = hist[tid]; scn[tid] = v; }
    __syncthreads();
#pragma unroll
    for (int off = 1; off < 256; off <<= 1) {
        int t = (tid >= off && tid < 256) ? scn[tid - off] : 0;
        __syncthreads();
        if (tid < 256) scn[tid] += t;
        __syncthreads();
    }
    if (tid < 256) {
        int excl = scn[tid] - v;
        scn[tid] = excl;
    }
    __syncthreads();

#pragma unroll
    for (int k = 0; k < 8; ++k) {
        int b = myb[k];
        if (b >= 0) {
            int slot = scn[b] + atomicAdd(&rcnt[b], 1);
            stage[slot] = mypk[k];
            bkts[slot] = (unsigned char)b;
        }
    }

    if (tid < 256 && hist[tid] > 0) gbase[tid] = atomicAdd(&bcur[tid], hist[tid]);
    __syncthreads();

    int total = scn[255] + hist[255];
    const int cap = 1 << SLAB_SHIFT;
    for (int s = tid; s < total; s += 512) {
        unsigned u = stage[s];
        int b = bkts[s];
        int off = gbase[b] + (s - scn[b]);
        if (off < cap)                              // clamp (pathological only)
            bins[((size_t)b << SLAB_SHIFT) + off] = u;
    }
}

// ---- per-bucket: degree count + local scan + scatter; emits rpse + dis ----
__global__ __launch_bounds__(1024) void k_fill2(const unsigned* __restrict__ bins,
                                                const int* __restrict__ bcur,
                                                int2* __restrict__ rpse,
                                                float* __restrict__ dis,
                                                int* __restrict__ pair, int N) {
    __shared__ int cnt[512];
    __shared__ int lcur[512];
    __shared__ int ssum[256];
    const int tid = threadIdx.x;
    const int b = blockIdx.x;
    const int n0 = b << FB_SHIFT;
    const int start = b << SLAB_SHIFT;
    int count = bcur[b];
    if (count > (1 << SLAB_SHIFT)) count = 1 << SLAB_SHIFT;
    const int end = start + count;

    if (tid < 512) cnt[tid] = 0;
    __syncthreads();

    for (int i = start + tid; i < end; i += 1024)
        atomicAdd(&cnt[bins[i] & ((1 << FB_SHIFT) - 1)], 1);
    __syncthreads();

    int c0 = 0, c1 = 0, vsum = 0;
    if (tid < 256) {
        c0 = cnt[2 * tid]; c1 = cnt[2 * tid + 1];
        vsum = c0 + c1;
        ssum[tid] = vsum;
    }
    __syncthreads();
#pragma unroll
    for (int off = 1; off < 256; off <<= 1) {
        int u = (tid >= off && tid < 256) ? ssum[tid - off] : 0;
        __syncthreads();
        if (tid < 256) ssum[tid] += u;
        __syncthreads();
    }
    if (tid < 256) {
        int e0 = start + ssum[tid] - vsum;
        int e1 = e0 + c0;
        lcur[2 * tid] = e0;
        lcur[2 * tid + 1] = e1;
        int node0 = n0 + 2 * tid;
        int node1 = node0 + 1;
        if (node0 < N) {
            rpse[node0] = make_int2(e0, e1);
            dis[node0] = rsqrtf((float)(c0 + 1));   // +1 self-loop
        }
        if (node1 < N) {
            rpse[node1] = make_int2(e1, e1 + c1);
            dis[node1] = rsqrtf((float)(c1 + 1));
        }
    }
    __syncthreads();

    for (int i = start + tid; i < end; i += 1024) {
        unsigned u = bins[i];
        int pos = atomicAdd(&lcur[u & ((1 << FB_SHIFT) - 1)], 1);
        pair[pos] = (int)(u >> FB_SHIFT);
    }
}

// ---- gather layer 1: xab[c] = bf16(dis[c]*(sum_r dis[r]*xb[r] + dis[c]*xb[c]))
// Wave per node; xb is RAW bf16; dis[r] scalar-loaded per edge (r is
// wave-uniform, dis table 400KB L2-resident); accumulate via fma (same
// VALU count as the pre-scaled add). At the structural floor otherwise.
__global__ __launch_bounds__(256) void k_gather1(const unsigned* __restrict__ xb,
                                                 const int2* __restrict__ rpse,
                                                 const int* __restrict__ pair,
                                                 const float* __restrict__ dis,
                                                 unsigned* __restrict__ xab, int N) {
    int gw = (blockIdx.x * 256 + threadIdx.x) >> 6;
    int lane = threadIdx.x & 63;
    if (gw >= N) return;
    float dv = dis[gw];
    unsigned us = xb[(size_t)gw * 64 + lane];
    float2 acc = make_float2(dv * bf_lo(us), dv * bf_hi(us));   // self term
    int2 rp = rpse[gw];
    int j = rp.x, je = rp.y;

    for (; j + 7 < je; j += 8) {
        int r0 = pair[j],     r1 = pair[j + 1], r2 = pair[j + 2], r3 = pair[j + 3];
        int r4 = pair[j + 4], r5 = pair[j + 5], r6 = pair[j + 6], r7 = pair[j + 7];
        float d0 = dis[r0], d1 = dis[r1], d2 = dis[r2], d3 = dis[r3];
        float d4 = dis[r4], d5 = dis[r5], d6 = dis[r6], d7 = dis[r7];
        unsigned a0 = xb[(size_t)r0 * 64 + lane];
        unsigned a1 = xb[(size_t)r1 * 64 + lane];
        unsigned a2 = xb[(size_t)r2 * 64 + lane];
        unsigned a3 = xb[(size_t)r3 * 64 + lane];
        unsigned a4 = xb[(size_t)r4 * 64 + lane];
        unsigned a5 = xb[(size_t)r5 * 64 + lane];
        unsigned a6 = xb[(size_t)r6 * 64 + lane];
        unsigned a7 = xb[(size_t)r7 * 64 + lane];
        acc.x = fmaf(d0, bf_lo(a0), acc.x); acc.y = fmaf(d0, bf_hi(a0), acc.y);
        acc.x = fmaf(d1, bf_lo(a1), acc.x); acc.y = fmaf(d1, bf_hi(a1), acc.y);
        acc.x = fmaf(d2, bf_lo(a2), acc.x); acc.y = fmaf(d2, bf_hi(a2), acc.y);
        acc.x = fmaf(d3, bf_lo(a3), acc.x); acc.y = fmaf(d3, bf_hi(a3), acc.y);
        acc.x = fmaf(d4, bf_lo(a4), acc.x); acc.y = fmaf(d4, bf_hi(a4), acc.y);
        acc.x = fmaf(d5, bf_lo(a5), acc.x); acc.y = fmaf(d5, bf_hi(a5), acc.y);
        acc.x = fmaf(d6, bf_lo(a6), acc.x); acc.y = fmaf(d6, bf_hi(a6), acc.y);
        acc.x = fmaf(d7, bf_lo(a7), acc.x); acc.y = fmaf(d7, bf_hi(a7), acc.y);
    }
    for (; j + 3 < je; j += 4) {
        int r0 = pair[j], r1 = pair[j + 1], r2 = pair[j + 2], r3 = pair[j + 3];
        float d0 = dis[r0], d1 = dis[r1], d2 = dis[r2], d3 = dis[r3];
        unsigned a0 = xb[(size_t)r0 * 64 + lane];
        unsigned a1 = xb[(size_t)r1 * 64 + lane];
        unsigned a2 = xb[(size_t)r2 * 64 + lane];
        unsigned a3 = xb[(size_t)r3 * 64 + lane];
        acc.x = fmaf(d0, bf_lo(a0), acc.x); acc.y = fmaf(d0, bf_hi(a0), acc.y);
        acc.x = fmaf(d1, bf_lo(a1), acc.x); acc.y = fmaf(d1, bf_hi(a1), acc.y);
        acc.x = fmaf(d2, bf_lo(a2), acc.x); acc.y = fmaf(d2, bf_hi(a2), acc.y);
        acc.x = fmaf(d3, bf_lo(a3), acc.x); acc.y = fmaf(d3, bf_hi(a3), acc.y);
    }
    for (; j < je; ++j) {
        int r0 = pair[j];
        float d0 = dis[r0];
        unsigned a0 = xb[(size_t)r0 * 64 + lane];
        acc.x = fmaf(d0, bf_lo(a0), acc.x); acc.y = fmaf(d0, bf_hi(a0), acc.y);
    }
    xab[(size_t)gw * 64 + lane] = bf16rn(dv * acc.x) | (bf16rn(dv * acc.y) << 16);
}

// ---- fused GEMM1+GEMM2 (MFMA bf16) ----------------------------------------
// h = relu(xab @ W1t^T + b1)  (h kept in LDS, never hits global)
// Zb[M, pitch 32] = bf16( (h @ W2t^T) * dis[row] )  (20 uints used, 12 pad)
__global__ __launch_bounds__(256) void k_gemm12(const unsigned* __restrict__ Ab,
                                                const unsigned* __restrict__ Wt,
                                                const unsigned* __restrict__ W2t,
                                                const float* __restrict__ bias,
                                                const float* __restrict__ dis,
                                                unsigned* __restrict__ Zb, int M) {
    __shared__ char smem[70144];            // 34816 + 34816 + 512 (ldis)
    char* Abase = smem;
    char* Bbase = smem + 34816;
    float* ldis = (float*)(smem + 69632);

    const int tid = threadIdx.x;
    const int r0 = blockIdx.x * 128;

#pragma unroll
    for (int s = 0; s < 8; ++s) {
        int l = tid + s * 256;
        int row = l >> 4, q = l & 15;
        uint4 va = *(const uint4*)(Ab + (size_t)(r0 + row) * 64 + q * 4);
        *(uint4*)(Abase + row * 272 + q * 16) = va;
        uint4 vb = *(const uint4*)(Wt + (size_t)row * 64 + q * 4);
        *(uint4*)(Bbase + row * 272 + q * 16) = vb;
    }
    if (tid < 128) {
        int rr = r0 + tid;
        ldis[tid] = (rr < M) ? dis[rr] : 0.f;
    }
    __syncthreads();

    const int wv = tid >> 6, lane = tid & 63;
    const int quad = lane >> 4, mcol = lane & 15;

    // ---------------- GEMM1: acc1 = xab @ W1t^T ----------------
    f32x4 acc1[2][8];
#pragma unroll
    for (int rt = 0; rt < 2; ++rt)
#pragma unroll
        for (int ct = 0; ct < 8; ++ct) acc1[rt][ct] = (f32x4){0.f, 0.f, 0.f, 0.f};

#pragma unroll
    for (int ks = 0; ks < 4; ++ks) {
        bf16x8 a[2], b[8];
#pragma unroll
        for (int rt = 0; rt < 2; ++rt) {
            int row = wv * 32 + rt * 16 + mcol;
            a[rt] = *(const bf16x8*)(Abase + row * 272 + ks * 64 + quad * 16);
        }
#pragma unroll
        for (int ct = 0; ct < 8; ++ct) {
            int n = ct * 16 + mcol;
            b[ct] = *(const bf16x8*)(Bbase + n * 272 + ks * 64 + quad * 16);
        }
#pragma unroll
        for (int rt = 0; rt < 2; ++rt)
#pragma unroll
            for (int ct = 0; ct < 8; ++ct)
                acc1[rt][ct] = __builtin_amdgcn_mfma_f32_16x16x32_bf16(
                    a[rt], b[ct], acc1[rt][ct], 0, 0, 0);
    }
    __syncthreads();     // all waves done reading As (xab) and Bs (W1)

    // h (relu + bias, bf16) -> Bs region; W2 tile -> As region
    unsigned short* Hs = (unsigned short*)Bbase;     // pitch 136 ushorts
#pragma unroll
    for (int rt = 0; rt < 2; ++rt)
#pragma unroll
        for (int ct = 0; ct < 8; ++ct) {
            float bb = bias[ct * 16 + mcol];
#pragma unroll
            for (int r = 0; r < 4; ++r) {
                float v = acc1[rt][ct][r] + bb;
                v = v > 0.f ? v : 0.f;
                int orow = wv * 32 + rt * 16 + quad * 4 + r;
                Hs[orow * 136 + ct * 16 + mcol] = (unsigned short)bf16rn(v);
            }
        }
#pragma unroll
    for (int s = 0; s < 3; ++s) {
        int l = tid + s * 256;
        int row = l >> 4, q = l & 15;
        uint4 vb = *(const uint4*)(W2t + (size_t)row * 64 + q * 4);
        *(uint4*)(Abase + row * 272 + q * 16) = vb;
    }
    __syncthreads();

    // ---------------- GEMM2: acc2 = h @ W2t^T ----------------
    f32x4 acc2[2][3];
#pragma unroll
    for (int rt = 0; rt < 2; ++rt)
#pragma unroll
        for (int ct = 0; ct < 3; ++ct) acc2[rt][ct] = (f32x4){0.f, 0.f, 0.f, 0.f};

#pragma unroll
    for (int ks = 0; ks < 4; ++ks) {
        bf16x8 a[2], b[3];
#pragma unroll
        for (int rt = 0; rt < 2; ++rt) {
            int row = wv * 32 + rt * 16 + mcol;
            a[rt] = *(const bf16x8*)(Bbase + row * 272 + ks * 64 + quad * 16);
        }
#pragma unroll
        for (int ct = 0; ct < 3; ++ct) {
            int n = ct * 16 + mcol;
            b[ct] = *(const bf16x8*)(Abase + n * 272 + ks * 64 + quad * 16);
        }
#pragma unroll
        for (int rt = 0; rt < 2; ++rt)
#pragma unroll
            for (int ct = 0; ct < 3; ++ct)
                acc2[rt][ct] = __builtin_amdgcn_mfma_f32_16x16x32_bf16(
                    a[rt], b[ct], acc2[rt][ct], 0, 0, 0);
    }
    __syncthreads();

    // epilogue: scale by dis[row], pack bf16 rows at 56-ushort pitch (112 B)
    unsigned short* Zs = (unsigned short*)(Abase + 16384);  // above W2 (13056 B)
#pragma unroll
    for (int rt = 0; rt < 2; ++rt)
#pragma unroll
        for (int ct = 0; ct < 3; ++ct) {
#pragma unroll
            for (int r = 0; r < 4; ++r) {
                int orow = wv * 32 + rt * 16 + quad * 4 + r;
                float v = acc2[rt][ct][r] * ldis[orow];
                Zs[orow * 56 + ct * 16 + mcol] = (unsigned short)bf16rn(v);
            }
        }
    __syncthreads();

    if (tid < 128) {
        int rr = r0 + tid;
        if (rr < M) {
            const uint4* s4 = (const uint4*)(Abase + 16384 + tid * 112);
            uint4* d4 = (uint4*)(Zb + ((size_t)rr << 5));   // pitch 32 uints
#pragma unroll
            for (int q = 0; q < 5; ++q) d4[q] = s4[q];
        }
    }
}

// ---- gather layer 2: out[c] = b2 + dis[c] * (sum_r zb[r] + zb[c]) ---------
// Half-wave per edge stream; 16 edges in flight (8 per half).
// zb pitch = 32 uints (128 B): one aligned cache line per random row.
__global__ __launch_bounds__(256) void k_gather2(const unsigned* __restrict__ zb,
                                                 const int2* __restrict__ rpse,
                                                 const int* __restrict__ pair,
                                                 const float* __restrict__ dis,
                                                 const float* __restrict__ b2,
                                                 float* __restrict__ out, int N) {
    int gw = (blockIdx.x * 256 + threadIdx.x) >> 6;
    int lane = threadIdx.x & 63;
    if (gw >= N) return;
    int sub = lane >> 5;
    int sl  = lane & 31;
    int f   = (sl < 20) ? sl : 19;

    float2 acc = make_float2(0.f, 0.f);
    float dv = dis[gw];
    if (sub == 0) {                       // self term (rows pre-scaled by dis)
        unsigned u = zb[((size_t)gw << 5) + f];
        acc.x = bf_lo(u); acc.y = bf_hi(u);
    }

    int2 rp = rpse[gw];
    int j = rp.x, je = rp.y;
    for (; j + 15 < je; j += 16) {
        int rA = pair[j + sub];
        int rB = pair[j + 2 + sub];
        int rC = pair[j + 4 + sub];
        int rD = pair[j + 6 + sub];
        int rE = pair[j + 8 + sub];
        int rF = pair[j + 10 + sub];
        int rG = pair[j + 12 + sub];
        int rH = pair[j + 14 + sub];
        unsigned uA = zb[((size_t)rA << 5) + f];
        unsigned uB = zb[((size_t)rB << 5) + f];
        unsigned uC = zb[((size_t)rC << 5) + f];
        unsigned uD = zb[((size_t)rD << 5) + f];
        unsigned uE = zb[((size_t)rE << 5) + f];
        unsigned uF = zb[((size_t)rF << 5) + f];
        unsigned uG = zb[((size_t)rG << 5) + f];
        unsigned uH = zb[((size_t)rH << 5) + f];
        acc.x += bf_lo(uA); acc.y += bf_hi(uA);
        acc.x += bf_lo(uB); acc.y += bf_hi(uB);
        acc.x += bf_lo(uC); acc.y += bf_hi(uC);
        acc.x += bf_lo(uD); acc.y += bf_hi(uD);
        acc.x += bf_lo(uE); acc.y += bf_hi(uE);
        acc.x += bf_lo(uF); acc.y += bf_hi(uF);
        acc.x += bf_lo(uG); acc.y += bf_hi(uG);
        acc.x += bf_lo(uH); acc.y += bf_hi(uH);
    }
    for (; j + 7 < je; j += 8) {
        int rA = pair[j + sub];
        int rB = pair[j + 2 + sub];
        int rC = pair[j + 4 + sub];
        int rD = pair[j + 6 + sub];
        unsigned uA = zb[((size_t)rA << 5) + f];
        unsigned uB = zb[((size_t)rB << 5) + f];
        unsigned uC = zb[((size_t)rC << 5) + f];
        unsigned uD = zb[((size_t)rD << 5) + f];
        acc.x += bf_lo(uA); acc.y += bf_hi(uA);
        acc.x += bf_lo(uB); acc.y += bf_hi(uB);
        acc.x += bf_lo(uC); acc.y += bf_hi(uC);
        acc.x += bf_lo(uD); acc.y += bf_hi(uD);
    }
    for (; j + 3 < je; j += 4) {
        int rA = pair[j + sub];
        int rB = pair[j + 2 + sub];
        unsigned uA = zb[((size_t)rA << 5) + f];
        unsigned uB = zb[((size_t)rB << 5) + f];
        acc.x += bf_lo(uA); acc.y += bf_hi(uA);
        acc.x += bf_lo(uB); acc.y += bf_hi(uB);
    }
    for (; j + 1 < je; j += 2) {
        unsigned u = zb[((size_t)pair[j + sub] << 5) + f];
        acc.x += bf_lo(u); acc.y += bf_hi(u);
    }
    if (j < je && sub == 0) {
        unsigned u = zb[((size_t)pair[j] << 5) + f];
        acc.x += bf_lo(u); acc.y += bf_hi(u);
    }

    float bx = __shfl(acc.x, sl + 32, 64);
    float by = __shfl(acc.y, sl + 32, 64);
    if (sub == 0 && sl < 20) {
        float2 bias = ((const float2*)b2)[sl];
        float2 res = make_float2((acc.x + bx) * dv + bias.x,
                                 (acc.y + by) * dv + bias.y);
        ((float2*)(out + (size_t)gw * 40))[sl] = res;
    }
}

// ---------------------------------------------------------------------------
extern "C" void kernel_launch(void* const* d_in, const int* in_sizes, int n_in,
                              void* d_out, int out_size, void* d_ws, size_t ws_size,
                              hipStream_t stream) {
    const float* x  = (const float*)d_in[0];
    const int*   ei = (const int*)d_in[1];
    const float* W1 = (const float*)d_in[2];
    const float* b1 = (const float*)d_in[3];
    const float* W2 = (const float*)d_in[4];
    const float* b2 = (const float*)d_in[5];
    float* out = (float*)d_out;

    const int N = in_sizes[0] / 128;
    const int E = in_sizes[1] / 2;
    const int* row = ei;        // sources
    const int* col = ei + E;    // targets

    const int Np = (N + 255) & ~255;
    const int nbuck = (N + (1 << FB_SHIFT) - 1) >> FB_SHIFT;   // <= 256
    const int nEB = (E + 4095) / 4096;
    const int nXB = (N * 32 + 511) / 512;                      // x-cvt tail blocks

    // workspace layout (4-byte units), ~82 MB total
    int*      bcur   = (int*)d_ws;                       // 256
    int2*     rpse   = (int2*)(bcur + 256);              // Np int2 (2*Np ints)
    float*    dis    = (float*)(rpse + Np);              // Np
    unsigned* Wt     = (unsigned*)(dis + Np);            // 8192 (W1t bf16)
    unsigned* W2t    = Wt + 8192;                        // 3072 (W2t bf16, 48 rows)
    int*      pair   = (int*)(W2t + 3072);               // 256<<14 slabbed
    unsigned* xb     = (unsigned*)(pair + ((size_t)256 << SLAB_SHIFT)); // N*64 raw
    unsigned* xab    = xb + (size_t)N * 64;              // N*64 (bf16 A*x)
    unsigned* zb     = xab + (size_t)N * 64;             // N*32 (bf16 z*dis, padded)
    unsigned* bins   = (unsigned*)xab;  // alias: slabbed, dead before gather1

    // slab-bucketed CSC build; tails also do W cvt + raw x cvt (no deps)
    hipMemsetAsync(bcur, 0, 256 * sizeof(int), stream);
    k_binfill<<<nEB + 22 + nXB, 512, 0, stream>>>(row, col, bcur, bins, E, nEB,
                                                  W1, W2, Wt, W2t, x, xb, N * 32);
    k_fill2<<<nbuck, 1024, 0, stream>>>(bins, bcur, rpse, dis, pair, N);

    // layer 1 gather: xab = bf16(A x)   (dis applied per edge, fma)
    k_gather1<<<(N + 3) / 4, 256, 0, stream>>>(xb, rpse, pair, dis, xab, N);

    // fused GEMMs: zb = bf16((relu(xab@W1+b1) @ W2) * dis)   [MFMA]
    k_gemm12<<<(N + 127) / 128, 256, 0, stream>>>(xab, Wt, W2t, b1, dis, zb, N);

    // layer 2 gather: out = b2 + dis*(sum zb)
    k_gather2<<<(N + 3) / 4, 256, 0, stream>>>(zb, rpse, pair, dis, b2, out, N);
}